// Round 3
// baseline (890.242 us; speedup 1.0000x reference)
//
#include <hip/hip_runtime.h>
#include <math.h>

#define B_   512
#define N_   193
#define D_   512
#define E_   2048
#define KTOK 96
#define H_   1024
#define M1   (B_ * KTOK)      // 49152
#define KGD  (KTOK * 4)       // 384

typedef _Float16 half8 __attribute__((ext_vector_type(8)));
typedef _Float16 half4v __attribute__((ext_vector_type(4)));
typedef float floatx4 __attribute__((ext_vector_type(4)));

// async global->LDS, 16B per lane; LDS dest = wave-uniform base + lane*16
__device__ __forceinline__ void gll16(const _Float16* g, _Float16* l) {
    __builtin_amdgcn_global_load_lds(
        (const __attribute__((address_space(1))) unsigned int*)(const void*)g,
        (__attribute__((address_space(3))) unsigned int*)(void*)l, 16, 0, 0);
}

// ---------------- K0: zero BN stats ----------------
__global__ void zero_stats_kernel(double* stats) {
    int i = blockIdx.x * 256 + threadIdx.x;
    if (i < 2 * H_) stats[i] = 0.0;
}

// ---------------- K1: exact stable top-k (rank count) ----------------
__global__ void topk_kernel(const float* __restrict__ atten, int* __restrict__ idx) {
    __shared__ float s[N_];
    int b = blockIdx.x;
    const float* row = atten + (size_t)b * N_ * N_;   // atten[b, 0, :]
    for (int i = threadIdx.x; i < N_; i += blockDim.x)
        s[i] = (i == 0) ? -1.0f : row[i];
    __syncthreads();
    for (int i = threadIdx.x; i < N_; i += blockDim.x) {
        float v = s[i];
        int rank = 0;
        for (int j = 0; j < N_; ++j) {
            float u = s[j];
            rank += (u > v) || (u == v && j < i);
        }
        if (rank < KTOK) idx[b * KTOK + rank] = i;
    }
}

// ---------------- K2: gather + l2norm -> Xh (f16) + dyn-proj stage 1 (Y) ----------------
__global__ __launch_bounds__(256) void gather_kernel(
        const float* __restrict__ base, const int* __restrict__ idx,
        const float* __restrict__ W_dyn, const float* __restrict__ b_dyn,
        _Float16* __restrict__ Xh, float* __restrict__ Y) {
    int rowid = blockIdx.x;                 // 0..49151 = b*96 + t
    int b = rowid / KTOK, t = rowid - b * KTOK;
    int tid = threadIdx.x;
    int tok = idx[rowid];
    const float* src = base + ((size_t)b * N_ + tok) * D_;
    float v0 = src[tid], v1 = src[tid + 256];

    float vals[5];
    vals[0] = v0 * v0 + v1 * v1;
#pragma unroll
    for (int r = 0; r < 4; ++r)
        vals[1 + r] = v0 * W_dyn[r * D_ + tid] + v1 * W_dyn[r * D_ + tid + 256];

    __shared__ float red[5][4];
    __shared__ float tot[5];
    int lane = tid & 63, wid = tid >> 6;
#pragma unroll
    for (int c = 0; c < 5; ++c) {
        float v = vals[c];
        for (int o = 32; o > 0; o >>= 1) v += __shfl_down(v, o, 64);
        if (lane == 0) red[c][wid] = v;
    }
    __syncthreads();
    if (tid < 5) tot[tid] = red[tid][0] + red[tid][1] + red[tid][2] + red[tid][3];
    __syncthreads();

    float norm = sqrtf(tot[0]) + 1e-8f;
    size_t xb = (size_t)rowid * D_;
    Xh[xb + tid]       = (_Float16)(v0 / norm);
    Xh[xb + tid + 256] = (_Float16)(v1 / norm);
    if (tid == 0) {
        int g = b >> 2;
        int n = (b & 3) * KTOK + t;
#pragma unroll
        for (int r = 0; r < 4; ++r)
            Y[(size_t)(g * 4 + r) * KGD + n] = tot[1 + r] + b_dyn[r];
    }
}

// ---------------- K3: new_feats = l2norm(Y @ W_lin^T + b_lin) (fp32, small) ----------------
__global__ __launch_bounds__(256) void newfeat_kernel(
        const float* __restrict__ Y, const float* __restrict__ W_lin,
        const float* __restrict__ b_lin, float* __restrict__ NF) {
    __shared__ float sy[4][KGD];
    __shared__ float red[4][4];
    __shared__ float tot[4];
    int b0 = blockIdx.x * 4;
    int tid = threadIdx.x;
    for (int l = tid; l < 4 * KGD; l += 256)
        sy[l / KGD][l % KGD] = Y[(size_t)b0 * KGD + l];
    __syncthreads();

    float out[4][8];
    float ssq[4] = {0.f, 0.f, 0.f, 0.f};
#pragma unroll
    for (int q = 0; q < 8; ++q) {
        int o = tid + 256 * q;
        float a0 = 0.f, a1 = 0.f, a2 = 0.f, a3 = 0.f;
        const float4* wr = (const float4*)(W_lin + (size_t)o * KGD);
        for (int i4 = 0; i4 < KGD / 4; ++i4) {
            float4 w  = wr[i4];
            float4 s0 = *(const float4*)&sy[0][i4 * 4];
            float4 s1 = *(const float4*)&sy[1][i4 * 4];
            float4 s2 = *(const float4*)&sy[2][i4 * 4];
            float4 s3 = *(const float4*)&sy[3][i4 * 4];
            a0 += w.x * s0.x + w.y * s0.y + w.z * s0.z + w.w * s0.w;
            a1 += w.x * s1.x + w.y * s1.y + w.z * s1.z + w.w * s1.w;
            a2 += w.x * s2.x + w.y * s2.y + w.z * s2.z + w.w * s2.w;
            a3 += w.x * s3.x + w.y * s3.y + w.z * s3.z + w.w * s3.w;
        }
        float bl = b_lin[o];
        out[0][q] = a0 + bl; out[1][q] = a1 + bl;
        out[2][q] = a2 + bl; out[3][q] = a3 + bl;
#pragma unroll
        for (int r = 0; r < 4; ++r) ssq[r] += out[r][q] * out[r][q];
    }

    int lane = tid & 63, wid = tid >> 6;
#pragma unroll
    for (int c = 0; c < 4; ++c) {
        float v = ssq[c];
        for (int o = 32; o > 0; o >>= 1) v += __shfl_down(v, o, 64);
        if (lane == 0) red[c][wid] = v;
    }
    __syncthreads();
    if (tid < 4) tot[tid] = red[tid][0] + red[tid][1] + red[tid][2] + red[tid][3];
    __syncthreads();
#pragma unroll
    for (int r = 0; r < 4; ++r) {
        float norm = sqrtf(tot[r]) + 1e-8f;
#pragma unroll
        for (int q = 0; q < 8; ++q) {
            int o = tid + 256 * q;
            NF[(size_t)(b0 + r) * E_ + o] = out[r][q] / norm;
        }
    }
}

// ---------------- K4: convert W1, W2 to f16 ----------------
__global__ __launch_bounds__(256) void convw_kernel(
        const float* __restrict__ W1, const float* __restrict__ W2,
        _Float16* __restrict__ W1h, _Float16* __restrict__ W2h) {
    int i = blockIdx.x * 256 + threadIdx.x;
    if (i < 131072) {                       // W1: 1024*512/4
        float4 v = *(const float4*)&W1[(size_t)i * 4];
        half4v o = {(_Float16)v.x, (_Float16)v.y, (_Float16)v.z, (_Float16)v.w};
        *(half4v*)&W1h[(size_t)i * 4] = o;
    } else {                                // W2: 2048*1024/4
        int j = i - 131072;
        float4 v = *(const float4*)&W2[(size_t)j * 4];
        half4v o = {(_Float16)v.x, (_Float16)v.y, (_Float16)v.z, (_Float16)v.w};
        *(half4v*)&W2h[(size_t)j * 4] = o;
    }
}

// ---------------- ring-buffer MFMA GEMM: tile 192x256, BK=32, 4-slot ring ----------------
// A [M x K_] row-major f16 (M-tile padded staging to 256 rows, reads use 192),
// B [Nn x K_] row-major f16 (output col = B row). 512 thr = 8 waves (2M x 4N),
// wave = 96x64 out = 6x4 frags of 16x16, 24 MFMA / K-step.
// MODE 1: C = A@B^T + bias -> f16 [M x 1024]
// MODE 2: out[batch] = max over 96 rows (per wave-half) + bias + NF  (fused maxpool)
template<int K_, int MODE>
__global__ __launch_bounds__(512, 2) void gemm_ring(
        const _Float16* __restrict__ A, const _Float16* __restrict__ Bm,
        const float* __restrict__ bias, const float* __restrict__ NF,
        _Float16* __restrict__ Cf16, float* __restrict__ out) {
    constexpr int NKT = K_ / 32;
    __shared__ _Float16 Al[4][8192];    // slot: [4 kg][256 rows][8]
    __shared__ _Float16 Bl[4][8192];    // slot: [4 kg][256 cols][8]
    int tid = threadIdx.x;
    int ln = tid & 63, w = tid >> 6;
    int wr = w >> 2, wc = w & 3;
    int n0 = blockIdx.x * 256, m0 = blockIdx.y * 192;

    // staging: wave w issues chunk-insts {2w, 2w+1} for A and for B.
    // chunk j (0..15): kg = j>>2, row = (j&3)*64 + lane.
    int ja = 2 * w, jb = 2 * w + 1;
    const _Float16* sA0 = A  + (size_t)(m0 + (ja & 3) * 64 + ln) * K_ + (ja >> 2) * 8;
    const _Float16* sA1 = A  + (size_t)(m0 + (jb & 3) * 64 + ln) * K_ + (jb >> 2) * 8;
    const _Float16* sB0 = Bm + (size_t)(n0 + (ja & 3) * 64 + ln) * K_ + (ja >> 2) * 8;
    const _Float16* sB1 = Bm + (size_t)(n0 + (jb & 3) * 64 + ln) * K_ + (jb >> 2) * 8;
    int la0 = ja * 512, la1 = jb * 512;   // wave-uniform LDS chunk bases (elems)

#define RSTAGE(sl, kt) { int ko = (kt) * 32;                 \
    gll16(sA0 + ko, &Al[sl][la0]); gll16(sA1 + ko, &Al[sl][la1]); \
    gll16(sB0 + ko, &Bl[sl][la0]); gll16(sB1 + ko, &Bl[sl][la1]); }

    // ds_read fragment offsets (elems): A row = wr*96 + f*16 + (ln&15), kg = ln>>4
    int aoff[6], boff[4];
#pragma unroll
    for (int f = 0; f < 6; ++f)
        aoff[f] = ((ln >> 4) * 256 + wr * 96 + f * 16 + (ln & 15)) * 8;
#pragma unroll
    for (int nj = 0; nj < 4; ++nj)
        boff[nj] = ((ln >> 4) * 256 + wc * 64 + nj * 16 + (ln & 15)) * 8;

    floatx4 zero = {0.f, 0.f, 0.f, 0.f};
    floatx4 acc[6][4];
#pragma unroll
    for (int i = 0; i < 6; ++i)
#pragma unroll
        for (int j = 0; j < 4; ++j) acc[i][j] = zero;

    RSTAGE(0, 0); RSTAGE(1, 1); RSTAGE(2, 2);        // 12 insts in flight
    for (int kt = 0; kt < NKT; ++kt) {
        int sl = kt & 3;
        if (kt + 3 < NKT) RSTAGE((kt + 3) & 3, kt + 3);
        // counted vmcnt: keep up to 3 tiles (12 insts) in flight; tile kt landed
        if (kt < NKT - 3)       asm volatile("s_waitcnt vmcnt(12)" ::: "memory");
        else if (kt == NKT - 3) asm volatile("s_waitcnt vmcnt(8)"  ::: "memory");
        else if (kt == NKT - 2) asm volatile("s_waitcnt vmcnt(4)"  ::: "memory");
        else                    asm volatile("s_waitcnt vmcnt(0)"  ::: "memory");
        __builtin_amdgcn_s_barrier();
        __builtin_amdgcn_sched_barrier(0);
        half8 af[6], bf[4];
#pragma unroll
        for (int f = 0; f < 6; ++f)  af[f]  = *(const half8*)&Al[sl][aoff[f]];
#pragma unroll
        for (int nj = 0; nj < 4; ++nj) bf[nj] = *(const half8*)&Bl[sl][boff[nj]];
        __builtin_amdgcn_s_setprio(1);
#pragma unroll
        for (int f = 0; f < 6; ++f)
#pragma unroll
            for (int nj = 0; nj < 4; ++nj)
                acc[f][nj] = __builtin_amdgcn_mfma_f32_16x16x32_f16(af[f], bf[nj], acc[f][nj], 0, 0, 0);
        __builtin_amdgcn_s_setprio(0);
        __builtin_amdgcn_sched_barrier(0);
        __builtin_amdgcn_s_barrier();    // protects slot (kt)&3 from next iter's stage
    }
#undef RSTAGE

    if (MODE == 1) {
        // C/D layout: col = ln&15, row = (ln>>4)*4 + r
#pragma unroll
        for (int f = 0; f < 6; ++f) {
            int row = m0 + wr * 96 + f * 16 + (ln >> 4) * 4;
#pragma unroll
            for (int nj = 0; nj < 4; ++nj) {
                int col = n0 + wc * 64 + nj * 16 + (ln & 15);
                float bb = bias[col];
#pragma unroll
                for (int r = 0; r < 4; ++r)
                    Cf16[(size_t)(row + r) * H_ + col] = (_Float16)(acc[f][nj][r] + bb);
            }
        }
    } else {
        int batch = blockIdx.y * 2 + wr;    // wave half wr owns one full batch (96 rows)
#pragma unroll
        for (int nj = 0; nj < 4; ++nj) {
            float m = -3.4e38f;
#pragma unroll
            for (int f = 0; f < 6; ++f)
#pragma unroll
                for (int r = 0; r < 4; ++r) m = fmaxf(m, acc[f][nj][r]);
            m = fmaxf(m, __shfl_xor(m, 16));
            m = fmaxf(m, __shfl_xor(m, 32));
            if (ln < 16) {
                int col = n0 + wc * 64 + nj * 16 + ln;
                out[(size_t)batch * E_ + col] = m + bias[col] + NF[(size_t)batch * E_ + col];
            }
        }
    }
}

// ---------------- K6: BN column stats from f16 Hb ----------------
__global__ __launch_bounds__(256) void stats_kernel(
        const _Float16* __restrict__ Hbh, double* __restrict__ stats) {
    int blk = blockIdx.x, tid = threadIdx.x;
    int c0 = tid * 4;
    double s[4] = {0, 0, 0, 0}, q[4] = {0, 0, 0, 0};
    for (int r = 0; r < 96; ++r) {
        const half4v v = *(const half4v*)&Hbh[(size_t)(blk * 96 + r) * H_ + c0];
#pragma unroll
        for (int c = 0; c < 4; ++c) {
            float f = (float)v[c];
            s[c] += f;
            q[c] += (double)f * (double)f;
        }
    }
#pragma unroll
    for (int c = 0; c < 4; ++c) {
        atomicAdd(&stats[c0 + c], s[c]);
        atomicAdd(&stats[H_ + c0 + c], q[c]);
    }
}

// ---------------- K7: finalize BN -> scale/shift ----------------
__global__ void finalize_kernel(const double* __restrict__ stats,
                                const float* __restrict__ gamma,
                                const float* __restrict__ beta,
                                float* __restrict__ scsh) {
    int c = blockIdx.x * 256 + threadIdx.x;
    if (c >= H_) return;
    double mean = stats[c] / (double)M1;
    double var  = stats[H_ + c] / (double)M1 - mean * mean;
    float sc = gamma[c] * (float)(1.0 / sqrt(var + 1e-5));
    float sh = beta[c] - (float)mean * sc;
    scsh[c] = sc;
    scsh[H_ + c] = sh;
}

// ---------------- K8: BN-apply + ReLU -> A2h (f16) ----------------
__global__ __launch_bounds__(256) void bnrelu_kernel(
        const _Float16* __restrict__ Hbh, const float* __restrict__ scsh,
        _Float16* __restrict__ A2h) {
    size_t i = (size_t)blockIdx.x * 256 + threadIdx.x;
    size_t e0 = i * 8;
    int col0 = (int)(e0 & (H_ - 1));
    half8 v = *(const half8*)&Hbh[e0];
    float4 sc0 = *(const float4*)&scsh[col0];
    float4 sc1 = *(const float4*)&scsh[col0 + 4];
    float4 sh0 = *(const float4*)&scsh[H_ + col0];
    float4 sh1 = *(const float4*)&scsh[H_ + col0 + 4];
    half8 o;
    o[0] = (_Float16)fmaxf(0.f, (float)v[0] * sc0.x + sh0.x);
    o[1] = (_Float16)fmaxf(0.f, (float)v[1] * sc0.y + sh0.y);
    o[2] = (_Float16)fmaxf(0.f, (float)v[2] * sc0.z + sh0.z);
    o[3] = (_Float16)fmaxf(0.f, (float)v[3] * sc0.w + sh0.w);
    o[4] = (_Float16)fmaxf(0.f, (float)v[4] * sc1.x + sh1.x);
    o[5] = (_Float16)fmaxf(0.f, (float)v[5] * sc1.y + sh1.y);
    o[6] = (_Float16)fmaxf(0.f, (float)v[6] * sc1.z + sh1.z);
    o[7] = (_Float16)fmaxf(0.f, (float)v[7] * sc1.w + sh1.w);
    *(half8*)&A2h[e0] = o;
}

// ---------------- launch ----------------
extern "C" void kernel_launch(void* const* d_in, const int* in_sizes, int n_in,
                              void* d_out, int out_size, void* d_ws, size_t ws_size,
                              hipStream_t stream) {
    (void)in_sizes; (void)n_in; (void)out_size; (void)ws_size;
    const float* base  = (const float*)d_in[0];
    const float* atten = (const float*)d_in[1];
    // d_in[2] = pid: unused (uniform contiguous groups of 4 by construction)
    const float* W_dyn = (const float*)d_in[3];
    const float* b_dyn = (const float*)d_in[4];
    const float* W_lin = (const float*)d_in[5];
    const float* b_lin = (const float*)d_in[6];
    const float* W1    = (const float*)d_in[7];
    const float* b1    = (const float*)d_in[8];
    const float* gamma = (const float*)d_in[9];
    const float* beta  = (const float*)d_in[10];
    const float* W2    = (const float*)d_in[11];
    const float* b2    = (const float*)d_in[12];
    float* out = (float*)d_out;

    char* wsp = (char*)d_ws;
    int*      idx   = (int*)(wsp);                       // 196608 B
    float*    Y     = (float*)(wsp + 196608);            // 786432 B
    float*    NF    = (float*)(wsp + 983040);            // 4 MB
    double*   stats = (double*)(wsp + 5177344);          // 16 KB
    float*    scsh  = (float*)(wsp + 5193728);           // 8 KB
    _Float16* W1h   = (_Float16*)(wsp + 5201920);        // 1 MB
    _Float16* W2h   = (_Float16*)(wsp + 6250496);        // 4 MB
    _Float16* Xh    = (_Float16*)(wsp + 10444800);       // (49152+64)x512 f16 = 50.4 MB
    _Float16* Hbh   = (_Float16*)(wsp + 60841984);       // 49152x1024 f16 = 100.7 MB
    _Float16* A2h   = (_Float16*)(wsp + 161505280);      // (49152+64)x1024 f16 = 100.8 MB
                                                         // total ~250 MiB

    zero_stats_kernel<<<8, 256, 0, stream>>>(stats);
    topk_kernel<<<B_, 256, 0, stream>>>(atten, idx);
    convw_kernel<<<2560, 256, 0, stream>>>(W1, W2, W1h, W2h);
    gather_kernel<<<M1, 256, 0, stream>>>(base, idx, W_dyn, b_dyn, Xh, Y);
    newfeat_kernel<<<B_ / 4, 256, 0, stream>>>(Y, W_lin, b_lin, NF);
    gemm_ring<512, 1><<<dim3(H_ / 256, M1 / 192), 512, 0, stream>>>(
        Xh, W1h, b1, nullptr, Hbh, nullptr);
    stats_kernel<<<B_, 256, 0, stream>>>(Hbh, stats);
    finalize_kernel<<<4, 256, 0, stream>>>(stats, gamma, beta, scsh);
    bnrelu_kernel<<<(M1 * H_ / 8) / 256, 256, 0, stream>>>(Hbh, scsh, A2h);
    gemm_ring<1024, 2><<<dim3(E_ / 256, M1 / 192), 512, 0, stream>>>(
        A2h, W2h, b2, NF, nullptr, out);
}

// Round 4
// 838.648 us; speedup vs baseline: 1.0615x; 1.0615x over previous
//
#include <hip/hip_runtime.h>
#include <math.h>

#define B_   512
#define N_   193
#define D_   512
#define E_   2048
#define KTOK 96
#define H_   1024
#define M1   (B_ * KTOK)      // 49152
#define KGD  (KTOK * 4)       // 384

typedef _Float16 half8 __attribute__((ext_vector_type(8)));
typedef _Float16 half4v __attribute__((ext_vector_type(4)));
typedef float floatx4 __attribute__((ext_vector_type(4)));

// async global->LDS, 16B per lane; LDS dest = wave-uniform base + lane*16
__device__ __forceinline__ void gll16(const _Float16* g, _Float16* l) {
    __builtin_amdgcn_global_load_lds(
        (const __attribute__((address_space(1))) unsigned int*)(const void*)g,
        (__attribute__((address_space(3))) unsigned int*)(void*)l, 16, 0, 0);
}

// ---------------- K0: zero BN stats ----------------
__global__ void zero_stats_kernel(double* stats) {
    int i = blockIdx.x * 256 + threadIdx.x;
    if (i < 2 * H_) stats[i] = 0.0;
}

// ---------------- K1: exact stable top-k (rank count) ----------------
__global__ void topk_kernel(const float* __restrict__ atten, int* __restrict__ idx) {
    __shared__ float s[N_];
    int b = blockIdx.x;
    const float* row = atten + (size_t)b * N_ * N_;   // atten[b, 0, :]
    for (int i = threadIdx.x; i < N_; i += blockDim.x)
        s[i] = (i == 0) ? -1.0f : row[i];
    __syncthreads();
    for (int i = threadIdx.x; i < N_; i += blockDim.x) {
        float v = s[i];
        int rank = 0;
        for (int j = 0; j < N_; ++j) {
            float u = s[j];
            rank += (u > v) || (u == v && j < i);
        }
        if (rank < KTOK) idx[b * KTOK + rank] = i;
    }
}

// ---------------- K2: gather + l2norm -> Xh (f16) + dyn-proj stage 1 (Y) ----------------
__global__ __launch_bounds__(256) void gather_kernel(
        const float* __restrict__ base, const int* __restrict__ idx,
        const float* __restrict__ W_dyn, const float* __restrict__ b_dyn,
        _Float16* __restrict__ Xh, float* __restrict__ Y) {
    int rowid = blockIdx.x;                 // 0..49151 = b*96 + t
    int b = rowid / KTOK, t = rowid - b * KTOK;
    int tid = threadIdx.x;
    int tok = idx[rowid];
    const float* src = base + ((size_t)b * N_ + tok) * D_;
    float v0 = src[tid], v1 = src[tid + 256];

    float vals[5];
    vals[0] = v0 * v0 + v1 * v1;
#pragma unroll
    for (int r = 0; r < 4; ++r)
        vals[1 + r] = v0 * W_dyn[r * D_ + tid] + v1 * W_dyn[r * D_ + tid + 256];

    __shared__ float red[5][4];
    __shared__ float tot[5];
    int lane = tid & 63, wid = tid >> 6;
#pragma unroll
    for (int c = 0; c < 5; ++c) {
        float v = vals[c];
        for (int o = 32; o > 0; o >>= 1) v += __shfl_down(v, o, 64);
        if (lane == 0) red[c][wid] = v;
    }
    __syncthreads();
    if (tid < 5) tot[tid] = red[tid][0] + red[tid][1] + red[tid][2] + red[tid][3];
    __syncthreads();

    float norm = sqrtf(tot[0]) + 1e-8f;
    size_t xb = (size_t)rowid * D_;
    Xh[xb + tid]       = (_Float16)(v0 / norm);
    Xh[xb + tid + 256] = (_Float16)(v1 / norm);
    if (tid == 0) {
        int g = b >> 2;
        int n = (b & 3) * KTOK + t;
#pragma unroll
        for (int r = 0; r < 4; ++r)
            Y[(size_t)(g * 4 + r) * KGD + n] = tot[1 + r] + b_dyn[r];
    }
}

// ---------------- K3: new_feats = l2norm(Y @ W_lin^T + b_lin) (fp32, small) ----------------
__global__ __launch_bounds__(256) void newfeat_kernel(
        const float* __restrict__ Y, const float* __restrict__ W_lin,
        const float* __restrict__ b_lin, float* __restrict__ NF) {
    __shared__ float sy[4][KGD];
    __shared__ float red[4][4];
    __shared__ float tot[4];
    int b0 = blockIdx.x * 4;
    int tid = threadIdx.x;
    for (int l = tid; l < 4 * KGD; l += 256)
        sy[l / KGD][l % KGD] = Y[(size_t)b0 * KGD + l];
    __syncthreads();

    float out[4][8];
    float ssq[4] = {0.f, 0.f, 0.f, 0.f};
#pragma unroll
    for (int q = 0; q < 8; ++q) {
        int o = tid + 256 * q;
        float a0 = 0.f, a1 = 0.f, a2 = 0.f, a3 = 0.f;
        const float4* wr = (const float4*)(W_lin + (size_t)o * KGD);
        for (int i4 = 0; i4 < KGD / 4; ++i4) {
            float4 w  = wr[i4];
            float4 s0 = *(const float4*)&sy[0][i4 * 4];
            float4 s1 = *(const float4*)&sy[1][i4 * 4];
            float4 s2 = *(const float4*)&sy[2][i4 * 4];
            float4 s3 = *(const float4*)&sy[3][i4 * 4];
            a0 += w.x * s0.x + w.y * s0.y + w.z * s0.z + w.w * s0.w;
            a1 += w.x * s1.x + w.y * s1.y + w.z * s1.z + w.w * s1.w;
            a2 += w.x * s2.x + w.y * s2.y + w.z * s2.z + w.w * s2.w;
            a3 += w.x * s3.x + w.y * s3.y + w.z * s3.z + w.w * s3.w;
        }
        float bl = b_lin[o];
        out[0][q] = a0 + bl; out[1][q] = a1 + bl;
        out[2][q] = a2 + bl; out[3][q] = a3 + bl;
#pragma unroll
        for (int r = 0; r < 4; ++r) ssq[r] += out[r][q] * out[r][q];
    }

    int lane = tid & 63, wid = tid >> 6;
#pragma unroll
    for (int c = 0; c < 4; ++c) {
        float v = ssq[c];
        for (int o = 32; o > 0; o >>= 1) v += __shfl_down(v, o, 64);
        if (lane == 0) red[c][wid] = v;
    }
    __syncthreads();
    if (tid < 4) tot[tid] = red[tid][0] + red[tid][1] + red[tid][2] + red[tid][3];
    __syncthreads();
#pragma unroll
    for (int r = 0; r < 4; ++r) {
        float norm = sqrtf(tot[r]) + 1e-8f;
#pragma unroll
        for (int q = 0; q < 8; ++q) {
            int o = tid + 256 * q;
            NF[(size_t)(b0 + r) * E_ + o] = out[r][q] / norm;
        }
    }
}

// ---------------- K4: convert W1, W2 to f16 ----------------
__global__ __launch_bounds__(256) void convw_kernel(
        const float* __restrict__ W1, const float* __restrict__ W2,
        _Float16* __restrict__ W1h, _Float16* __restrict__ W2h) {
    int i = blockIdx.x * 256 + threadIdx.x;
    if (i < 131072) {                       // W1: 1024*512/4
        float4 v = *(const float4*)&W1[(size_t)i * 4];
        half4v o = {(_Float16)v.x, (_Float16)v.y, (_Float16)v.z, (_Float16)v.w};
        *(half4v*)&W1h[(size_t)i * 4] = o;
    } else {                                // W2: 2048*1024/4
        int j = i - 131072;
        float4 v = *(const float4*)&W2[(size_t)j * 4];
        half4v o = {(_Float16)v.x, (_Float16)v.y, (_Float16)v.z, (_Float16)v.w};
        *(half4v*)&W2h[(size_t)j * 4] = o;
    }
}

// ---------------- 8-phase MFMA GEMM (m201-style): BM=192, BN=256, BK=64 ----------------
// A [M x KA] row-major f16, Bm [Nn x KA] row-major f16 (out col = Bm row).
// 512 thr = 8 waves (2M x 4N); wave tile 96x64 = 6x4 frags; 48 MFMA / K-tile.
// Per K-tile: 4 phases; phase = quadrant (mq,nq): {10 ds_read_b128; stage 2-3 gll;
// sched_barrier; [p3: vmcnt(0)]; s_barrier; lgkmcnt(0); sched_barrier; setprio(1);
// 12 MFMA; setprio(0); sched_barrier; s_barrier}.
// MODE 1: C = A@B^T + bias -> f16 [M x H_]
// MODE 2: out[batch] = maxpool over 96 rows (wave-half) + bias + NF
template<int KA, int MODE>
__global__ __launch_bounds__(512, 2) void gemm8p(
        const _Float16* __restrict__ A, const _Float16* __restrict__ Bm,
        const float* __restrict__ bias, const float* __restrict__ NF,
        _Float16* __restrict__ Cf16, float* __restrict__ out) {
    constexpr int NT = KA / 64;
    __shared__ _Float16 Ab[2][12288];   // [8 kg][192 rows][8]
    __shared__ _Float16 Bb[2][16384];   // [8 kg][256 cols][8]
    int tid = threadIdx.x;
    int ln = tid & 63, w = tid >> 6;
    int wr = w >> 2, wc = w & 3;
    int n0 = blockIdx.x * 256, m0 = blockIdx.y * 192;

    // staging chunks: A 24 x 1KB (3/wave), B 32 x 1KB (4/wave)
    const _Float16 *sA[3], *sB[4];
    int lA[3], lB[4];
#pragma unroll
    for (int i = 0; i < 3; ++i) {
        int c = w + i * 8;
        int u = c * 64 + ln;
        int kg = u / 192, row = u - kg * 192;
        sA[i] = A + (size_t)(m0 + row) * KA + kg * 8;
        lA[i] = c * 512;
    }
#pragma unroll
    for (int i = 0; i < 4; ++i) {
        int c = w + i * 8;
        int u = c * 64 + ln;
        int kg = u >> 8, col = u & 255;
        sB[i] = Bm + (size_t)(n0 + col) * KA + kg * 8;
        lB[i] = c * 512;
    }

#define STG_A(i, T, bf) gll16(sA[i] + (size_t)(T) * 64, (_Float16*)&Ab[bf][lA[i]])
#define STG_B(i, T, bf) gll16(sB[i] + (size_t)(T) * 64, (_Float16*)&Bb[bf][lB[i]])
#define STAGE0(T, bf) { STG_A(0, T, bf); STG_B(0, T, bf); STG_B(1, T, bf); }
#define STAGE1(T, bf) { STG_A(1, T, bf); STG_B(2, T, bf); }
#define STAGE2(T, bf) { STG_A(2, T, bf); STG_B(3, T, bf); }

    // ds_read fragment offsets (f16 elems)
    int aoff[6][2], boff[4][2];
#pragma unroll
    for (int f = 0; f < 6; ++f)
#pragma unroll
        for (int s = 0; s < 2; ++s)
            aoff[f][s] = ((s * 4 + (ln >> 4)) * 192 + wr * 96 + f * 16 + (ln & 15)) * 8;
#pragma unroll
    for (int n = 0; n < 4; ++n)
#pragma unroll
        for (int s = 0; s < 2; ++s)
            boff[n][s] = ((s * 4 + (ln >> 4)) * 256 + wc * 64 + n * 16 + (ln & 15)) * 8;

    floatx4 zero = {0.f, 0.f, 0.f, 0.f};
    floatx4 acc[6][4];
#pragma unroll
    for (int i = 0; i < 6; ++i)
#pragma unroll
        for (int j = 0; j < 4; ++j) acc[i][j] = zero;

    // prologue: stage K-tile 0 fully
    STAGE0(0, 0); STAGE1(0, 0); STAGE2(0, 0);
    asm volatile("s_waitcnt vmcnt(0)" ::: "memory");
    __builtin_amdgcn_s_barrier();

    for (int T = 0; T < NT; ++T) {
        int bf = T & 1;
        const _Float16* Abf = Ab[bf];
        const _Float16* Bbf = Bb[bf];
        bool pre = (T + 1 < NT);
#pragma unroll
        for (int p = 0; p < 4; ++p) {
            const int mq = p >> 1, nq = p & 1;
            // ds_reads for this phase's quadrant (latency hides under barrier)
            half8 av[3][2], bv[2][2];
#pragma unroll
            for (int s = 0; s < 2; ++s) {
#pragma unroll
                for (int f3 = 0; f3 < 3; ++f3)
                    av[f3][s] = *(const half8*)&Abf[aoff[mq * 3 + f3][s]];
#pragma unroll
                for (int n2 = 0; n2 < 2; ++n2)
                    bv[n2][s] = *(const half8*)&Bbf[boff[nq * 2 + n2][s]];
            }
            // stage next K-tile into other buffer (phases 0-2)
            if (pre) {
                if (p == 0) STAGE0(T + 1, bf ^ 1);
                if (p == 1) STAGE1(T + 1, bf ^ 1);
                if (p == 2) STAGE2(T + 1, bf ^ 1);
            }
            __builtin_amdgcn_sched_barrier(0);
            if (p == 3) asm volatile("s_waitcnt vmcnt(0)" ::: "memory");
            __builtin_amdgcn_s_barrier();
            asm volatile("s_waitcnt lgkmcnt(0)" ::: "memory");
            __builtin_amdgcn_sched_barrier(0);
            __builtin_amdgcn_s_setprio(1);
#pragma unroll
            for (int s = 0; s < 2; ++s)
#pragma unroll
                for (int f3 = 0; f3 < 3; ++f3)
#pragma unroll
                    for (int n2 = 0; n2 < 2; ++n2)
                        acc[mq * 3 + f3][nq * 2 + n2] = __builtin_amdgcn_mfma_f32_16x16x32_f16(
                            av[f3][s], bv[n2][s], acc[mq * 3 + f3][nq * 2 + n2], 0, 0, 0);
            __builtin_amdgcn_s_setprio(0);
            __builtin_amdgcn_sched_barrier(0);
            __builtin_amdgcn_s_barrier();
        }
    }
#undef STG_A
#undef STG_B
#undef STAGE0
#undef STAGE1
#undef STAGE2

    if (MODE == 1) {
        // C/D layout: col = ln&15, row = (ln>>4)*4 + r
#pragma unroll
        for (int f = 0; f < 6; ++f) {
            int row = m0 + wr * 96 + f * 16 + (ln >> 4) * 4;
#pragma unroll
            for (int n = 0; n < 4; ++n) {
                int col = n0 + wc * 64 + n * 16 + (ln & 15);
                float bb = bias[col];
#pragma unroll
                for (int r = 0; r < 4; ++r)
                    Cf16[(size_t)(row + r) * H_ + col] = (_Float16)(acc[f][n][r] + bb);
            }
        }
    } else {
        int batch = blockIdx.y * 2 + wr;    // wave half wr owns one batch (96 rows)
#pragma unroll
        for (int n = 0; n < 4; ++n) {
            float m = -3.4e38f;
#pragma unroll
            for (int f = 0; f < 6; ++f)
#pragma unroll
                for (int r = 0; r < 4; ++r) m = fmaxf(m, acc[f][n][r]);
            m = fmaxf(m, __shfl_xor(m, 16));
            m = fmaxf(m, __shfl_xor(m, 32));
            if (ln < 16) {
                int col = n0 + wc * 64 + n * 16 + ln;
                out[(size_t)batch * E_ + col] = m + bias[col] + NF[(size_t)batch * E_ + col];
            }
        }
    }
}

// ---------------- K6: BN column stats from f16 Hb ----------------
__global__ __launch_bounds__(256) void stats_kernel(
        const _Float16* __restrict__ Hbh, double* __restrict__ stats) {
    int blk = blockIdx.x, tid = threadIdx.x;
    int c0 = tid * 4;
    double s[4] = {0, 0, 0, 0}, q[4] = {0, 0, 0, 0};
    for (int r = 0; r < 96; ++r) {
        const half4v v = *(const half4v*)&Hbh[(size_t)(blk * 96 + r) * H_ + c0];
#pragma unroll
        for (int c = 0; c < 4; ++c) {
            float f = (float)v[c];
            s[c] += f;
            q[c] += (double)f * (double)f;
        }
    }
#pragma unroll
    for (int c = 0; c < 4; ++c) {
        atomicAdd(&stats[c0 + c], s[c]);
        atomicAdd(&stats[H_ + c0 + c], q[c]);
    }
}

// ---------------- K7: finalize BN -> scale/shift ----------------
__global__ void finalize_kernel(const double* __restrict__ stats,
                                const float* __restrict__ gamma,
                                const float* __restrict__ beta,
                                float* __restrict__ scsh) {
    int c = blockIdx.x * 256 + threadIdx.x;
    if (c >= H_) return;
    double mean = stats[c] / (double)M1;
    double var  = stats[H_ + c] / (double)M1 - mean * mean;
    float sc = gamma[c] * (float)(1.0 / sqrt(var + 1e-5));
    float sh = beta[c] - (float)mean * sc;
    scsh[c] = sc;
    scsh[H_ + c] = sh;
}

// ---------------- K8: BN-apply + ReLU -> A2h (f16) ----------------
__global__ __launch_bounds__(256) void bnrelu_kernel(
        const _Float16* __restrict__ Hbh, const float* __restrict__ scsh,
        _Float16* __restrict__ A2h) {
    size_t i = (size_t)blockIdx.x * 256 + threadIdx.x;
    size_t e0 = i * 8;
    int col0 = (int)(e0 & (H_ - 1));
    half8 v = *(const half8*)&Hbh[e0];
    float4 sc0 = *(const float4*)&scsh[col0];
    float4 sc1 = *(const float4*)&scsh[col0 + 4];
    float4 sh0 = *(const float4*)&scsh[H_ + col0];
    float4 sh1 = *(const float4*)&scsh[H_ + col0 + 4];
    half8 o;
    o[0] = (_Float16)fmaxf(0.f, (float)v[0] * sc0.x + sh0.x);
    o[1] = (_Float16)fmaxf(0.f, (float)v[1] * sc0.y + sh0.y);
    o[2] = (_Float16)fmaxf(0.f, (float)v[2] * sc0.z + sh0.z);
    o[3] = (_Float16)fmaxf(0.f, (float)v[3] * sc0.w + sh0.w);
    o[4] = (_Float16)fmaxf(0.f, (float)v[4] * sc1.x + sh1.x);
    o[5] = (_Float16)fmaxf(0.f, (float)v[5] * sc1.y + sh1.y);
    o[6] = (_Float16)fmaxf(0.f, (float)v[6] * sc1.z + sh1.z);
    o[7] = (_Float16)fmaxf(0.f, (float)v[7] * sc1.w + sh1.w);
    *(half8*)&A2h[e0] = o;
}

// ---------------- launch ----------------
extern "C" void kernel_launch(void* const* d_in, const int* in_sizes, int n_in,
                              void* d_out, int out_size, void* d_ws, size_t ws_size,
                              hipStream_t stream) {
    (void)in_sizes; (void)n_in; (void)out_size; (void)ws_size;
    const float* base  = (const float*)d_in[0];
    const float* atten = (const float*)d_in[1];
    // d_in[2] = pid: unused (uniform contiguous groups of 4 by construction)
    const float* W_dyn = (const float*)d_in[3];
    const float* b_dyn = (const float*)d_in[4];
    const float* W_lin = (const float*)d_in[5];
    const float* b_lin = (const float*)d_in[6];
    const float* W1    = (const float*)d_in[7];
    const float* b1    = (const float*)d_in[8];
    const float* gamma = (const float*)d_in[9];
    const float* beta  = (const float*)d_in[10];
    const float* W2    = (const float*)d_in[11];
    const float* b2    = (const float*)d_in[12];
    float* out = (float*)d_out;

    char* wsp = (char*)d_ws;
    int*      idx   = (int*)(wsp);                       // 196608 B
    float*    Y     = (float*)(wsp + 196608);            // 786432 B
    float*    NF    = (float*)(wsp + 983040);            // 4 MB
    double*   stats = (double*)(wsp + 5177344);          // 16 KB
    float*    scsh  = (float*)(wsp + 5193728);           // 8 KB
    _Float16* W1h   = (_Float16*)(wsp + 5201920);        // 1 MB
    _Float16* W2h   = (_Float16*)(wsp + 6250496);        // 4 MB
    _Float16* Xh    = (_Float16*)(wsp + 10444800);       // 49152x512 f16 = 50.3 MB
    _Float16* Hbh   = (_Float16*)(wsp + 60776448);       // 49152x1024 f16 = 100.7 MB
    _Float16* A2h   = (_Float16*)(wsp + 161439744);      // 49152x1024 f16 = 100.7 MB
                                                         // total ~250 MiB

    zero_stats_kernel<<<8, 256, 0, stream>>>(stats);
    topk_kernel<<<B_, 256, 0, stream>>>(atten, idx);
    convw_kernel<<<2560, 256, 0, stream>>>(W1, W2, W1h, W2h);
    gather_kernel<<<M1, 256, 0, stream>>>(base, idx, W_dyn, b_dyn, Xh, Y);
    newfeat_kernel<<<B_ / 4, 256, 0, stream>>>(Y, W_lin, b_lin, NF);
    gemm8p<512, 1><<<dim3(H_ / 256, M1 / 192), 512, 0, stream>>>(
        Xh, W1h, b1, nullptr, Hbh, nullptr);
    stats_kernel<<<B_, 256, 0, stream>>>(Hbh, stats);
    finalize_kernel<<<4, 256, 0, stream>>>(stats, gamma, beta, scsh);
    bnrelu_kernel<<<(M1 * H_ / 8) / 256, 256, 0, stream>>>(Hbh, scsh, A2h);
    gemm8p<1024, 2><<<dim3(E_ / 256, M1 / 192), 512, 0, stream>>>(
        A2h, W2h, b2, NF, nullptr, out);
}

// Round 5
// 695.464 us; speedup vs baseline: 1.2801x; 1.2059x over previous
//
#include <hip/hip_runtime.h>
#include <math.h>

#define B_   512
#define N_   193
#define D_   512
#define E_   2048
#define KTOK 96
#define H_   1024
#define M1   (B_ * KTOK)      // 49152
#define KGD  (KTOK * 4)       // 384

typedef _Float16 half8 __attribute__((ext_vector_type(8)));
typedef _Float16 half4v __attribute__((ext_vector_type(4)));
typedef float floatx4 __attribute__((ext_vector_type(4)));

// async global->LDS, 16B per lane; LDS dest = wave-uniform base + lane*16
__device__ __forceinline__ void gll16(const _Float16* g, _Float16* l) {
    __builtin_amdgcn_global_load_lds(
        (const __attribute__((address_space(1))) unsigned int*)(const void*)g,
        (__attribute__((address_space(3))) unsigned int*)(void*)l, 16, 0, 0);
}

// ---------------- K0: zero BN stats ----------------
__global__ void zero_stats_kernel(double* stats) {
    int i = blockIdx.x * 256 + threadIdx.x;
    if (i < 2 * H_) stats[i] = 0.0;
}

// ---------------- K1: exact stable top-k (rank count) ----------------
__global__ void topk_kernel(const float* __restrict__ atten, int* __restrict__ idx) {
    __shared__ float s[N_];
    int b = blockIdx.x;
    const float* row = atten + (size_t)b * N_ * N_;   // atten[b, 0, :]
    for (int i = threadIdx.x; i < N_; i += blockDim.x)
        s[i] = (i == 0) ? -1.0f : row[i];
    __syncthreads();
    for (int i = threadIdx.x; i < N_; i += blockDim.x) {
        float v = s[i];
        int rank = 0;
        for (int j = 0; j < N_; ++j) {
            float u = s[j];
            rank += (u > v) || (u == v && j < i);
        }
        if (rank < KTOK) idx[b * KTOK + rank] = i;
    }
}

// ---------------- K2: gather + l2norm -> Xh (f16) + dyn-proj stage 1 (Y) ----------------
__global__ __launch_bounds__(256) void gather_kernel(
        const float* __restrict__ base, const int* __restrict__ idx,
        const float* __restrict__ W_dyn, const float* __restrict__ b_dyn,
        _Float16* __restrict__ Xh, float* __restrict__ Y) {
    int rowid = blockIdx.x;                 // 0..49151 = b*96 + t
    int b = rowid / KTOK, t = rowid - b * KTOK;
    int tid = threadIdx.x;
    int tok = idx[rowid];
    const float* src = base + ((size_t)b * N_ + tok) * D_;
    float v0 = src[tid], v1 = src[tid + 256];

    float vals[5];
    vals[0] = v0 * v0 + v1 * v1;
#pragma unroll
    for (int r = 0; r < 4; ++r)
        vals[1 + r] = v0 * W_dyn[r * D_ + tid] + v1 * W_dyn[r * D_ + tid + 256];

    __shared__ float red[5][4];
    __shared__ float tot[5];
    int lane = tid & 63, wid = tid >> 6;
#pragma unroll
    for (int c = 0; c < 5; ++c) {
        float v = vals[c];
        for (int o = 32; o > 0; o >>= 1) v += __shfl_down(v, o, 64);
        if (lane == 0) red[c][wid] = v;
    }
    __syncthreads();
    if (tid < 5) tot[tid] = red[tid][0] + red[tid][1] + red[tid][2] + red[tid][3];
    __syncthreads();

    float norm = sqrtf(tot[0]) + 1e-8f;
    size_t xb = (size_t)rowid * D_;
    Xh[xb + tid]       = (_Float16)(v0 / norm);
    Xh[xb + tid + 256] = (_Float16)(v1 / norm);
    if (tid == 0) {
        int g = b >> 2;
        int n = (b & 3) * KTOK + t;
#pragma unroll
        for (int r = 0; r < 4; ++r)
            Y[(size_t)(g * 4 + r) * KGD + n] = tot[1 + r] + b_dyn[r];
    }
}

// ---------------- K3: new_feats = l2norm(Y @ W_lin^T + b_lin) (fp32, small) ----------------
__global__ __launch_bounds__(256) void newfeat_kernel(
        const float* __restrict__ Y, const float* __restrict__ W_lin,
        const float* __restrict__ b_lin, float* __restrict__ NF) {
    __shared__ float sy[4][KGD];
    __shared__ float red[4][4];
    __shared__ float tot[4];
    int b0 = blockIdx.x * 4;
    int tid = threadIdx.x;
    for (int l = tid; l < 4 * KGD; l += 256)
        sy[l / KGD][l % KGD] = Y[(size_t)b0 * KGD + l];
    __syncthreads();

    float out[4][8];
    float ssq[4] = {0.f, 0.f, 0.f, 0.f};
#pragma unroll
    for (int q = 0; q < 8; ++q) {
        int o = tid + 256 * q;
        float a0 = 0.f, a1 = 0.f, a2 = 0.f, a3 = 0.f;
        const float4* wr = (const float4*)(W_lin + (size_t)o * KGD);
        for (int i4 = 0; i4 < KGD / 4; ++i4) {
            float4 w  = wr[i4];
            float4 s0 = *(const float4*)&sy[0][i4 * 4];
            float4 s1 = *(const float4*)&sy[1][i4 * 4];
            float4 s2 = *(const float4*)&sy[2][i4 * 4];
            float4 s3 = *(const float4*)&sy[3][i4 * 4];
            a0 += w.x * s0.x + w.y * s0.y + w.z * s0.z + w.w * s0.w;
            a1 += w.x * s1.x + w.y * s1.y + w.z * s1.z + w.w * s1.w;
            a2 += w.x * s2.x + w.y * s2.y + w.z * s2.z + w.w * s2.w;
            a3 += w.x * s3.x + w.y * s3.y + w.z * s3.z + w.w * s3.w;
        }
        float bl = b_lin[o];
        out[0][q] = a0 + bl; out[1][q] = a1 + bl;
        out[2][q] = a2 + bl; out[3][q] = a3 + bl;
#pragma unroll
        for (int r = 0; r < 4; ++r) ssq[r] += out[r][q] * out[r][q];
    }

    int lane = tid & 63, wid = tid >> 6;
#pragma unroll
    for (int c = 0; c < 4; ++c) {
        float v = ssq[c];
        for (int o = 32; o > 0; o >>= 1) v += __shfl_down(v, o, 64);
        if (lane == 0) red[c][wid] = v;
    }
    __syncthreads();
    if (tid < 4) tot[tid] = red[tid][0] + red[tid][1] + red[tid][2] + red[tid][3];
    __syncthreads();
#pragma unroll
    for (int r = 0; r < 4; ++r) {
        float norm = sqrtf(tot[r]) + 1e-8f;
#pragma unroll
        for (int q = 0; q < 8; ++q) {
            int o = tid + 256 * q;
            NF[(size_t)(b0 + r) * E_ + o] = out[r][q] / norm;
        }
    }
}

// ---------------- K4: convert W1, W2 to f16 ----------------
__global__ __launch_bounds__(256) void convw_kernel(
        const float* __restrict__ W1, const float* __restrict__ W2,
        _Float16* __restrict__ W1h, _Float16* __restrict__ W2h) {
    int i = blockIdx.x * 256 + threadIdx.x;
    if (i < 131072) {                       // W1: 1024*512/4
        float4 v = *(const float4*)&W1[(size_t)i * 4];
        half4v o = {(_Float16)v.x, (_Float16)v.y, (_Float16)v.z, (_Float16)v.w};
        *(half4v*)&W1h[(size_t)i * 4] = o;
    } else {                                // W2: 2048*1024/4
        int j = i - 131072;
        float4 v = *(const float4*)&W2[(size_t)j * 4];
        half4v o = {(_Float16)v.x, (_Float16)v.y, (_Float16)v.z, (_Float16)v.w};
        *(half4v*)&W2h[(size_t)j * 4] = o;
    }
}

// ---------- counted-vmcnt 4-slot MFMA GEMM: BM=192, BN=256, slot=K32 ----------
// A [M x KA] rm f16, Bm [Nn x KA] rm f16 (out col = Bm row). 512 thr = 8 waves
// (2M x 4N); wave tile 96x64 = 6x4 frags. Slot = 28 KB (A 12KB + B 16KB), ring
// of 4 = 112 KB LDS. Staging role-split: waves 0-3 stage A (3 gll/slot),
// waves 4-7 stage B (4 gll/slot). 3 slots in flight; counted vmcnt (A:6 / B:8
// steady) placed one phase BEFORE first consumption -> ds_reads always target
// landed slots; never drains to 0 mid-loop (T3+T4). T1 XCD swizzle: the NBX
// n-blocks sharing an A-panel map to one XCD (rid = (by&7) + 8*(bx + NBX*(by>>3))).
// MODE 1: C = A@B^T + bias -> f16 [M x H_]
// MODE 2: out[batch] = maxpool over 96 rows (wave-half) + bias + NF
template<int KA, int MODE, int NBX>
__global__ __launch_bounds__(512, 2) void gemm_cnt(
        const _Float16* __restrict__ A, const _Float16* __restrict__ Bm,
        const float* __restrict__ bias, const float* __restrict__ NF,
        _Float16* __restrict__ Cf16, float* __restrict__ out) {
    constexpr int NS = KA / 32;             // K32 slots
    __shared__ _Float16 Sl[4][14336];       // slot: A [4kg][192][8] | B [4kg][256][8]
    int tid = threadIdx.x;
    int ln = tid & 63, w = tid >> 6;
    int wr = w >> 2, wc = w & 3;

    // XCD-aware decode (8 XCDs; nwg = 8*NBX*(MB/8), balanced & bijective)
    int rid = blockIdx.x;
    int q = rid >> 3;
    int bx = q & (NBX - 1);
    int by = ((q / NBX) << 3) | (rid & 7);
    int n0 = bx * 256, m0 = by * 192;

    // staging sources (role-split)
    bool isA = (w < 4);
    const _Float16* sg[4];
    int ld[4];
    if (isA) {
#pragma unroll
        for (int i = 0; i < 3; ++i) {
            int j = w * 3 + i;              // 0..11
            int u = j * 64 + ln;            // 0..767
            int kg = u / 192, row = u - kg * 192;
            sg[i] = A + (size_t)(m0 + row) * KA + kg * 8;
            ld[i] = j * 512;
        }
        sg[3] = sg[0]; ld[3] = ld[0];
    } else {
#pragma unroll
        for (int i = 0; i < 4; ++i) {
            int j = (w - 4) * 4 + i;        // 0..15
            int u = j * 64 + ln;            // 0..1023
            int kg = u >> 8, col = u & 255;
            sg[i] = Bm + (size_t)(n0 + col) * KA + kg * 8;
            ld[i] = 6144 + j * 512;
        }
    }

#define CSTAGE(s) { int ko = (s) * 32; _Float16* dst = &Sl[(s) & 3][0];       \
    if (isA) { gll16(sg[0] + ko, dst + ld[0]); gll16(sg[1] + ko, dst + ld[1]); \
               gll16(sg[2] + ko, dst + ld[2]); }                               \
    else     { gll16(sg[0] + ko, dst + ld[0]); gll16(sg[1] + ko, dst + ld[1]); \
               gll16(sg[2] + ko, dst + ld[2]); gll16(sg[3] + ko, dst + ld[3]); } }
#define WAITV(na, nb) { if (isA) asm volatile("s_waitcnt vmcnt(" #na ")" ::: "memory"); \
                        else     asm volatile("s_waitcnt vmcnt(" #nb ")" ::: "memory"); }

    // ds_read fragment offsets (f16 elems)
    int aofs[6], bofs[4];
#pragma unroll
    for (int f = 0; f < 6; ++f)
        aofs[f] = ((ln >> 4) * 192 + wr * 96 + f * 16 + (ln & 15)) * 8;
#pragma unroll
    for (int n = 0; n < 4; ++n)
        bofs[n] = 6144 + ((ln >> 4) * 256 + wc * 64 + n * 16 + (ln & 15)) * 8;

    floatx4 zero = {0.f, 0.f, 0.f, 0.f};
    floatx4 acc[6][4];
#pragma unroll
    for (int i = 0; i < 6; ++i)
#pragma unroll
        for (int j = 0; j < 4; ++j) acc[i][j] = zero;

    // prologue: 3 slots in flight; ensure slot 0 landed (2 slots keep flying)
    CSTAGE(0); CSTAGE(1); CSTAGE(2);
    WAITV(6, 8);
    __builtin_amdgcn_s_barrier();

    for (int s = 0; s < NS; ++s) {
        const _Float16* SL = &Sl[s & 3][0];
        // ---- phase 0: B frags + A lower-half; stage slot s+3 ----
        half8 bv[4], av[3];
#pragma unroll
        for (int n = 0; n < 4; ++n) bv[n] = *(const half8*)&SL[bofs[n]];
#pragma unroll
        for (int f = 0; f < 3; ++f) av[f] = *(const half8*)&SL[aofs[f]];
        if (s + 3 < NS) CSTAGE(s + 3);
        __builtin_amdgcn_sched_barrier(0);
        __builtin_amdgcn_s_barrier();
        asm volatile("s_waitcnt lgkmcnt(0)" ::: "memory");
        __builtin_amdgcn_sched_barrier(0);
        __builtin_amdgcn_s_setprio(1);
#pragma unroll
        for (int f = 0; f < 3; ++f)
#pragma unroll
            for (int n = 0; n < 4; ++n)
                acc[f][n] = __builtin_amdgcn_mfma_f32_16x16x32_f16(av[f], bv[n], acc[f][n], 0, 0, 0);
        __builtin_amdgcn_s_setprio(0);
        __builtin_amdgcn_sched_barrier(0);
        __builtin_amdgcn_s_barrier();
        // ---- phase 1: A upper-half; counted wait for slot s+1 landing ----
        half8 av2[3];
#pragma unroll
        for (int f = 0; f < 3; ++f) av2[f] = *(const half8*)&SL[aofs[3 + f]];
        __builtin_amdgcn_sched_barrier(0);
        if (s + 1 < NS) {
            if (s + 3 < NS)      { WAITV(6, 8); }   // slots s+2,s+3 keep flying
            else if (s + 2 < NS) { WAITV(3, 4); }   // slot s+2 keeps flying
            else                 { WAITV(0, 0); }   // last prefetched slot
        }
        __builtin_amdgcn_s_barrier();
        asm volatile("s_waitcnt lgkmcnt(0)" ::: "memory");
        __builtin_amdgcn_sched_barrier(0);
        __builtin_amdgcn_s_setprio(1);
#pragma unroll
        for (int f = 0; f < 3; ++f)
#pragma unroll
            for (int n = 0; n < 4; ++n)
                acc[3 + f][n] = __builtin_amdgcn_mfma_f32_16x16x32_f16(av2[f], bv[n], acc[3 + f][n], 0, 0, 0);
        __builtin_amdgcn_s_setprio(0);
        __builtin_amdgcn_sched_barrier(0);
        __builtin_amdgcn_s_barrier();
    }
#undef CSTAGE
#undef WAITV

    if (MODE == 1) {
        // C/D layout: col = ln&15, row = (ln>>4)*4 + r
#pragma unroll
        for (int f = 0; f < 6; ++f) {
            int row = m0 + wr * 96 + f * 16 + (ln >> 4) * 4;
#pragma unroll
            for (int n = 0; n < 4; ++n) {
                int col = n0 + wc * 64 + n * 16 + (ln & 15);
                float bb = bias[col];
#pragma unroll
                for (int r = 0; r < 4; ++r)
                    Cf16[(size_t)(row + r) * H_ + col] = (_Float16)(acc[f][n][r] + bb);
            }
        }
    } else {
        int batch = by * 2 + wr;            // wave half wr owns one batch (96 rows)
#pragma unroll
        for (int n = 0; n < 4; ++n) {
            float m = -3.4e38f;
#pragma unroll
            for (int f = 0; f < 6; ++f)
#pragma unroll
                for (int r = 0; r < 4; ++r) m = fmaxf(m, acc[f][n][r]);
            m = fmaxf(m, __shfl_xor(m, 16));
            m = fmaxf(m, __shfl_xor(m, 32));
            if (ln < 16) {
                int col = n0 + wc * 64 + n * 16 + ln;
                out[(size_t)batch * E_ + col] = m + bias[col] + NF[(size_t)batch * E_ + col];
            }
        }
    }
}

// ---------------- K6: BN column stats from f16 Hb ----------------
__global__ __launch_bounds__(256) void stats_kernel(
        const _Float16* __restrict__ Hbh, double* __restrict__ stats) {
    int blk = blockIdx.x, tid = threadIdx.x;
    int c0 = tid * 4;
    double s[4] = {0, 0, 0, 0}, q[4] = {0, 0, 0, 0};
    for (int r = 0; r < 96; ++r) {
        const half4v v = *(const half4v*)&Hbh[(size_t)(blk * 96 + r) * H_ + c0];
#pragma unroll
        for (int c = 0; c < 4; ++c) {
            float f = (float)v[c];
            s[c] += f;
            q[c] += (double)f * (double)f;
        }
    }
#pragma unroll
    for (int c = 0; c < 4; ++c) {
        atomicAdd(&stats[c0 + c], s[c]);
        atomicAdd(&stats[H_ + c0 + c], q[c]);
    }
}

// ---------------- K7: finalize BN -> scale/shift ----------------
__global__ void finalize_kernel(const double* __restrict__ stats,
                                const float* __restrict__ gamma,
                                const float* __restrict__ beta,
                                float* __restrict__ scsh) {
    int c = blockIdx.x * 256 + threadIdx.x;
    if (c >= H_) return;
    double mean = stats[c] / (double)M1;
    double var  = stats[H_ + c] / (double)M1 - mean * mean;
    float sc = gamma[c] * (float)(1.0 / sqrt(var + 1e-5));
    float sh = beta[c] - (float)mean * sc;
    scsh[c] = sc;
    scsh[H_ + c] = sh;
}

// ---------------- K8: BN-apply + ReLU -> A2h (f16) ----------------
__global__ __launch_bounds__(256) void bnrelu_kernel(
        const _Float16* __restrict__ Hbh, const float* __restrict__ scsh,
        _Float16* __restrict__ A2h) {
    size_t i = (size_t)blockIdx.x * 256 + threadIdx.x;
    size_t e0 = i * 8;
    int col0 = (int)(e0 & (H_ - 1));
    half8 v = *(const half8*)&Hbh[e0];
    float4 sc0 = *(const float4*)&scsh[col0];
    float4 sc1 = *(const float4*)&scsh[col0 + 4];
    float4 sh0 = *(const float4*)&scsh[H_ + col0];
    float4 sh1 = *(const float4*)&scsh[H_ + col0 + 4];
    half8 o;
    o[0] = (_Float16)fmaxf(0.f, (float)v[0] * sc0.x + sh0.x);
    o[1] = (_Float16)fmaxf(0.f, (float)v[1] * sc0.y + sh0.y);
    o[2] = (_Float16)fmaxf(0.f, (float)v[2] * sc0.z + sh0.z);
    o[3] = (_Float16)fmaxf(0.f, (float)v[3] * sc0.w + sh0.w);
    o[4] = (_Float16)fmaxf(0.f, (float)v[4] * sc1.x + sh1.x);
    o[5] = (_Float16)fmaxf(0.f, (float)v[5] * sc1.y + sh1.y);
    o[6] = (_Float16)fmaxf(0.f, (float)v[6] * sc1.z + sh1.z);
    o[7] = (_Float16)fmaxf(0.f, (float)v[7] * sc1.w + sh1.w);
    *(half8*)&A2h[e0] = o;
}

// ---------------- launch ----------------
extern "C" void kernel_launch(void* const* d_in, const int* in_sizes, int n_in,
                              void* d_out, int out_size, void* d_ws, size_t ws_size,
                              hipStream_t stream) {
    (void)in_sizes; (void)n_in; (void)out_size; (void)ws_size;
    const float* base  = (const float*)d_in[0];
    const float* atten = (const float*)d_in[1];
    // d_in[2] = pid: unused (uniform contiguous groups of 4 by construction)
    const float* W_dyn = (const float*)d_in[3];
    const float* b_dyn = (const float*)d_in[4];
    const float* W_lin = (const float*)d_in[5];
    const float* b_lin = (const float*)d_in[6];
    const float* W1    = (const float*)d_in[7];
    const float* b1    = (const float*)d_in[8];
    const float* gamma = (const float*)d_in[9];
    const float* beta  = (const float*)d_in[10];
    const float* W2    = (const float*)d_in[11];
    const float* b2    = (const float*)d_in[12];
    float* out = (float*)d_out;

    char* wsp = (char*)d_ws;
    int*      idx   = (int*)(wsp);                       // 196608 B
    float*    Y     = (float*)(wsp + 196608);            // 786432 B
    float*    NF    = (float*)(wsp + 983040);            // 4 MB
    double*   stats = (double*)(wsp + 5177344);          // 16 KB
    float*    scsh  = (float*)(wsp + 5193728);           // 8 KB
    _Float16* W1h   = (_Float16*)(wsp + 5201920);        // 1 MB
    _Float16* W2h   = (_Float16*)(wsp + 6250496);        // 4 MB
    _Float16* Xh    = (_Float16*)(wsp + 10444800);       // 49152x512 f16 = 50.3 MB
    _Float16* Hbh   = (_Float16*)(wsp + 60776448);       // 49152x1024 f16 = 100.7 MB
    _Float16* A2h   = (_Float16*)(wsp + 161439744);      // 49152x1024 f16 = 100.7 MB
                                                         // total ~250 MiB

    zero_stats_kernel<<<8, 256, 0, stream>>>(stats);
    topk_kernel<<<B_, 256, 0, stream>>>(atten, idx);
    convw_kernel<<<2560, 256, 0, stream>>>(W1, W2, W1h, W2h);
    gather_kernel<<<M1, 256, 0, stream>>>(base, idx, W_dyn, b_dyn, Xh, Y);
    newfeat_kernel<<<B_ / 4, 256, 0, stream>>>(Y, W_lin, b_lin, NF);
    gemm_cnt<512, 1, 4><<<1024, 512, 0, stream>>>(Xh, W1h, b1, nullptr, Hbh, nullptr);
    stats_kernel<<<B_, 256, 0, stream>>>(Hbh, stats);
    finalize_kernel<<<4, 256, 0, stream>>>(stats, gamma, beta, scsh);
    bnrelu_kernel<<<(M1 * H_ / 8) / 256, 256, 0, stream>>>(Hbh, scsh, A2h);
    gemm_cnt<1024, 2, 8><<<2048, 512, 0, stream>>>(A2h, W2h, b2, NF, nullptr, out);
}

// Round 6
// 673.291 us; speedup vs baseline: 1.3222x; 1.0329x over previous
//
#include <hip/hip_runtime.h>
#include <math.h>

#define B_   512
#define N_   193
#define D_   512
#define E_   2048
#define KTOK 96
#define H_   1024
#define M1   (B_ * KTOK)      // 49152
#define KGD  (KTOK * 4)       // 384

typedef _Float16 half8 __attribute__((ext_vector_type(8)));
typedef _Float16 half4v __attribute__((ext_vector_type(4)));
typedef float floatx4 __attribute__((ext_vector_type(4)));

// async global->LDS, 16B per lane; LDS dest = wave-uniform base + lane*16
__device__ __forceinline__ void gll16(const _Float16* g, _Float16* l) {
    __builtin_amdgcn_global_load_lds(
        (const __attribute__((address_space(1))) unsigned int*)(const void*)g,
        (__attribute__((address_space(3))) unsigned int*)(void*)l, 16, 0, 0);
}

// ---------------- K0: zero BN stats ----------------
__global__ void zero_stats_kernel(double* stats) {
    int i = blockIdx.x * 256 + threadIdx.x;
    if (i < 2 * H_) stats[i] = 0.0;
}

// ---------------- K1: exact stable top-k (rank count) ----------------
__global__ void topk_kernel(const float* __restrict__ atten, int* __restrict__ idx) {
    __shared__ float s[N_];
    int b = blockIdx.x;
    const float* row = atten + (size_t)b * N_ * N_;   // atten[b, 0, :]
    for (int i = threadIdx.x; i < N_; i += blockDim.x)
        s[i] = (i == 0) ? -1.0f : row[i];
    __syncthreads();
    for (int i = threadIdx.x; i < N_; i += blockDim.x) {
        float v = s[i];
        int rank = 0;
        for (int j = 0; j < N_; ++j) {
            float u = s[j];
            rank += (u > v) || (u == v && j < i);
        }
        if (rank < KTOK) idx[b * KTOK + rank] = i;
    }
}

// ---------------- K2: gather + l2norm -> Xh (f16) + dyn-proj stage 1 (Y) ----------------
// one wave per selected row; float4 loads, butterfly reduce
__global__ __launch_bounds__(256) void gather_kernel(
        const float* __restrict__ base, const int* __restrict__ idx,
        const float* __restrict__ W_dyn, const float* __restrict__ b_dyn,
        _Float16* __restrict__ Xh, float* __restrict__ Y) {
    int ln = threadIdx.x & 63, wv = threadIdx.x >> 6;
    int rowid = blockIdx.x * 4 + wv;        // 0..49151 = b*96 + t
    int b = rowid / KTOK, t = rowid - b * KTOK;
    int tok = idx[rowid];
    const float4* src = (const float4*)(base + ((size_t)b * N_ + tok) * D_);
    float4 v0 = src[ln * 2], v1 = src[ln * 2 + 1];

    float vals[5];
    vals[0] = v0.x * v0.x + v0.y * v0.y + v0.z * v0.z + v0.w * v0.w
            + v1.x * v1.x + v1.y * v1.y + v1.z * v1.z + v1.w * v1.w;
#pragma unroll
    for (int r = 0; r < 4; ++r) {
        const float4* wr = (const float4*)(W_dyn + r * D_);
        float4 w0 = wr[ln * 2], w1 = wr[ln * 2 + 1];
        vals[1 + r] = v0.x * w0.x + v0.y * w0.y + v0.z * w0.z + v0.w * w0.w
                    + v1.x * w1.x + v1.y * w1.y + v1.z * w1.z + v1.w * w1.w;
    }
#pragma unroll
    for (int c = 0; c < 5; ++c)
#pragma unroll
        for (int o = 32; o > 0; o >>= 1) vals[c] += __shfl_xor(vals[c], o, 64);

    float inv = 1.0f / (sqrtf(vals[0]) + 1e-8f);
    half8 o8;
    o8[0] = (_Float16)(v0.x * inv); o8[1] = (_Float16)(v0.y * inv);
    o8[2] = (_Float16)(v0.z * inv); o8[3] = (_Float16)(v0.w * inv);
    o8[4] = (_Float16)(v1.x * inv); o8[5] = (_Float16)(v1.y * inv);
    o8[6] = (_Float16)(v1.z * inv); o8[7] = (_Float16)(v1.w * inv);
    *(half8*)&Xh[(size_t)rowid * D_ + ln * 8] = o8;
    if (ln == 0) {
        int g = b >> 2;
        int n = (b & 3) * KTOK + t;
#pragma unroll
        for (int r = 0; r < 4; ++r)
            Y[(size_t)(g * 4 + r) * KGD + n] = vals[1 + r] + b_dyn[r];
    }
}

// ---------------- K3: new_feats = l2norm(Y @ W_lin^T + b_lin) (fp32, small) ----------------
__global__ __launch_bounds__(256) void newfeat_kernel(
        const float* __restrict__ Y, const float* __restrict__ W_lin,
        const float* __restrict__ b_lin, float* __restrict__ NF) {
    __shared__ float sy[4][KGD];
    __shared__ float red[4][4];
    __shared__ float tot[4];
    int b0 = blockIdx.x * 4;
    int tid = threadIdx.x;
    for (int l = tid; l < 4 * KGD; l += 256)
        sy[l / KGD][l % KGD] = Y[(size_t)b0 * KGD + l];
    __syncthreads();

    float out[4][8];
    float ssq[4] = {0.f, 0.f, 0.f, 0.f};
#pragma unroll
    for (int q = 0; q < 8; ++q) {
        int o = tid + 256 * q;
        float a0 = 0.f, a1 = 0.f, a2 = 0.f, a3 = 0.f;
        const float4* wr = (const float4*)(W_lin + (size_t)o * KGD);
        for (int i4 = 0; i4 < KGD / 4; ++i4) {
            float4 w  = wr[i4];
            float4 s0 = *(const float4*)&sy[0][i4 * 4];
            float4 s1 = *(const float4*)&sy[1][i4 * 4];
            float4 s2 = *(const float4*)&sy[2][i4 * 4];
            float4 s3 = *(const float4*)&sy[3][i4 * 4];
            a0 += w.x * s0.x + w.y * s0.y + w.z * s0.z + w.w * s0.w;
            a1 += w.x * s1.x + w.y * s1.y + w.z * s1.z + w.w * s1.w;
            a2 += w.x * s2.x + w.y * s2.y + w.z * s2.z + w.w * s2.w;
            a3 += w.x * s3.x + w.y * s3.y + w.z * s3.z + w.w * s3.w;
        }
        float bl = b_lin[o];
        out[0][q] = a0 + bl; out[1][q] = a1 + bl;
        out[2][q] = a2 + bl; out[3][q] = a3 + bl;
#pragma unroll
        for (int r = 0; r < 4; ++r) ssq[r] += out[r][q] * out[r][q];
    }

    int lane = tid & 63, wid = tid >> 6;
#pragma unroll
    for (int c = 0; c < 4; ++c) {
        float v = ssq[c];
        for (int o = 32; o > 0; o >>= 1) v += __shfl_down(v, o, 64);
        if (lane == 0) red[c][wid] = v;
    }
    __syncthreads();
    if (tid < 4) tot[tid] = red[tid][0] + red[tid][1] + red[tid][2] + red[tid][3];
    __syncthreads();
#pragma unroll
    for (int r = 0; r < 4; ++r) {
        float norm = sqrtf(tot[r]) + 1e-8f;
#pragma unroll
        for (int q = 0; q < 8; ++q) {
            int o = tid + 256 * q;
            NF[(size_t)(b0 + r) * E_ + o] = out[r][q] / norm;
        }
    }
}

// ---------------- K4: convert W1, W2 to f16 ----------------
__global__ __launch_bounds__(256) void convw_kernel(
        const float* __restrict__ W1, const float* __restrict__ W2,
        _Float16* __restrict__ W1h, _Float16* __restrict__ W2h) {
    int i = blockIdx.x * 256 + threadIdx.x;
    if (i < 131072) {                       // W1: 1024*512/4
        float4 v = *(const float4*)&W1[(size_t)i * 4];
        half4v o = {(_Float16)v.x, (_Float16)v.y, (_Float16)v.z, (_Float16)v.w};
        *(half4v*)&W1h[(size_t)i * 4] = o;
    } else {                                // W2: 2048*1024/4
        int j = i - 131072;
        float4 v = *(const float4*)&W2[(size_t)j * 4];
        half4v o = {(_Float16)v.x, (_Float16)v.y, (_Float16)v.z, (_Float16)v.w};
        *(half4v*)&W2h[(size_t)j * 4] = o;
    }
}

// ---- counted-vmcnt 4-slot MFMA GEMM: BM=192, BN=256, slot=K32, 12 waves ----
// A [M x KA] rm f16, Bm [Nn x KA] rm f16 (out col = Bm row). 768 thr = 12
// waves (3M x 4N); wave tile 64x64 = 4x4 frags, 16 MFMA/slot. Slot = 28 KB,
// ring of 4 = 112 KB LDS, 1 blk/CU, 3 waves/SIMD. Staging roles: waves 0-3
// stage A (3 gll/slot), waves 4-11 stage B (2 gll/slot). 3 slots in flight,
// counted vmcnt never 0 mid-loop; ONE barrier per slot (reads complete at
// lgkmcnt(0) before the closing barrier -> stage of s+3 cannot race them).
// T1 XCD swizzle: NBX n-blocks sharing an A-panel land on one XCD.
// MODE 1: C = A@B^T + bias -> f16 [M x H_]
// MODE 2: out = maxpool over 96-row batches + bias + NF (LDS partial combine)
template<int KA, int MODE, int NBX>
__global__ __launch_bounds__(768, 3) void gemm_cnt(
        const _Float16* __restrict__ A, const _Float16* __restrict__ Bm,
        const float* __restrict__ bias, const float* __restrict__ NF,
        _Float16* __restrict__ Cf16, float* __restrict__ out) {
    constexpr int NS = KA / 32;             // K32 slots
    __shared__ _Float16 Sl[4][14336];       // slot: A [4kg][192][8] | B [4kg][256][8]
    int tid = threadIdx.x;
    int ln = tid & 63, w = tid >> 6;
    int wr = w >> 2, wc = w & 3;            // 3M x 4N

    // XCD-aware decode (8 XCDs; nwg = 8*NBX*(MB/8), bijective)
    int rid = blockIdx.x;
    int q = rid >> 3;
    int bx = q & (NBX - 1);
    int by = ((q / NBX) << 3) | (rid & 7);
    int n0 = bx * 256, m0 = by * 192;

    // staging roles
    bool isA = (w < 4);
    const _Float16* sg[3];
    int ld[3];
    if (isA) {
#pragma unroll
        for (int i = 0; i < 3; ++i) {
            int j = w * 3 + i;              // 0..11
            int u = j * 64 + ln;            // 0..767
            int kg = u / 192, row = u - kg * 192;
            sg[i] = A + (size_t)(m0 + row) * KA + kg * 8;
            ld[i] = j * 512;
        }
    } else {
#pragma unroll
        for (int i = 0; i < 2; ++i) {
            int j = (w - 4) * 2 + i;        // 0..15
            int u = j * 64 + ln;            // 0..1023
            int kg = u >> 8, col = u & 255;
            sg[i] = Bm + (size_t)(n0 + col) * KA + kg * 8;
            ld[i] = 6144 + j * 512;
        }
        sg[2] = sg[0]; ld[2] = ld[0];
    }

#define CSTAGE(s) { int ko = (s) * 32; _Float16* dst = &Sl[(s) & 3][0];        \
    gll16(sg[0] + ko, dst + ld[0]); gll16(sg[1] + ko, dst + ld[1]);            \
    if (isA) gll16(sg[2] + ko, dst + ld[2]); }
#define WAITV(na, nb) { if (isA) asm volatile("s_waitcnt vmcnt(" #na ")" ::: "memory"); \
                        else     asm volatile("s_waitcnt vmcnt(" #nb ")" ::: "memory"); }

    // ds_read fragment offsets (f16 elems)
    int aofs[4], bofs[4];
#pragma unroll
    for (int f = 0; f < 4; ++f)
        aofs[f] = ((ln >> 4) * 192 + wr * 64 + f * 16 + (ln & 15)) * 8;
#pragma unroll
    for (int j = 0; j < 4; ++j)
        bofs[j] = 6144 + ((ln >> 4) * 256 + wc * 64 + j * 16 + (ln & 15)) * 8;

    floatx4 zero = {0.f, 0.f, 0.f, 0.f};
    floatx4 acc[4][4];
#pragma unroll
    for (int i = 0; i < 4; ++i)
#pragma unroll
        for (int j = 0; j < 4; ++j) acc[i][j] = zero;

    // prologue: 3 slots in flight; slot 0 landed (2 keep flying)
    CSTAGE(0); CSTAGE(1); CSTAGE(2);
    WAITV(6, 4);
    __builtin_amdgcn_s_barrier();

    for (int s = 0; s < NS; ++s) {
        const _Float16* SL = &Sl[s & 3][0];
        half8 av[4], bv[4];
#pragma unroll
        for (int f = 0; f < 4; ++f) av[f] = *(const half8*)&SL[aofs[f]];
#pragma unroll
        for (int j = 0; j < 4; ++j) bv[j] = *(const half8*)&SL[bofs[j]];
        if (s + 3 < NS) CSTAGE(s + 3);
        __builtin_amdgcn_sched_barrier(0);
        // counted wait: own stage of slot s+1 landed; deeper slots keep flying
        if (s + 3 < NS)      { WAITV(6, 4); }
        else if (s + 2 < NS) { WAITV(3, 2); }
        else if (s + 1 < NS) { WAITV(0, 0); }
        asm volatile("s_waitcnt lgkmcnt(0)" ::: "memory");
        __builtin_amdgcn_sched_barrier(0);
        __builtin_amdgcn_s_setprio(1);
#pragma unroll
        for (int f = 0; f < 4; ++f)
#pragma unroll
            for (int j = 0; j < 4; ++j)
                acc[f][j] = __builtin_amdgcn_mfma_f32_16x16x32_f16(av[f], bv[j], acc[f][j], 0, 0, 0);
        __builtin_amdgcn_s_setprio(0);
        __builtin_amdgcn_sched_barrier(0);
        __builtin_amdgcn_s_barrier();       // single barrier per slot
    }
#undef CSTAGE
#undef WAITV

    if (MODE == 1) {
        // C/D layout: col = ln&15, row = (ln>>4)*4 + r
#pragma unroll
        for (int f = 0; f < 4; ++f) {
            int row = m0 + wr * 64 + f * 16 + (ln >> 4) * 4;
#pragma unroll
            for (int j = 0; j < 4; ++j) {
                int col = n0 + wc * 64 + j * 16 + (ln & 15);
                float bb = bias[col];
#pragma unroll
                for (int r = 0; r < 4; ++r)
                    Cf16[(size_t)(row + r) * H_ + col] = (_Float16)(acc[f][j][r] + bb);
            }
        }
    } else {
        // fused maxpool: wave rows wr*64..wr*64+63; batch0 = rows 0-95, batch1 = 96-191
        float* part = (float*)&Sl[0][0];    // [2 batch][2 contrib][256 col]
#pragma unroll
        for (int j = 0; j < 4; ++j) {
            int colw = wc * 64 + j * 16;
            if (wr == 0) {
                float m = -3.4e38f;
#pragma unroll
                for (int f = 0; f < 4; ++f)
#pragma unroll
                    for (int r = 0; r < 4; ++r) m = fmaxf(m, acc[f][j][r]);
                m = fmaxf(m, __shfl_xor(m, 16));
                m = fmaxf(m, __shfl_xor(m, 32));
                if (ln < 16) part[(0 * 2 + 0) * 256 + colw + ln] = m;
            } else if (wr == 1) {
                float m01 = -3.4e38f, m23 = -3.4e38f;
#pragma unroll
                for (int r = 0; r < 4; ++r) {
                    m01 = fmaxf(m01, fmaxf(acc[0][j][r], acc[1][j][r]));
                    m23 = fmaxf(m23, fmaxf(acc[2][j][r], acc[3][j][r]));
                }
                m01 = fmaxf(m01, __shfl_xor(m01, 16));
                m01 = fmaxf(m01, __shfl_xor(m01, 32));
                m23 = fmaxf(m23, __shfl_xor(m23, 16));
                m23 = fmaxf(m23, __shfl_xor(m23, 32));
                if (ln < 16) {
                    part[(0 * 2 + 1) * 256 + colw + ln] = m01;
                    part[(1 * 2 + 0) * 256 + colw + ln] = m23;
                }
            } else {
                float m = -3.4e38f;
#pragma unroll
                for (int f = 0; f < 4; ++f)
#pragma unroll
                    for (int r = 0; r < 4; ++r) m = fmaxf(m, acc[f][j][r]);
                m = fmaxf(m, __shfl_xor(m, 16));
                m = fmaxf(m, __shfl_xor(m, 32));
                if (ln < 16) part[(1 * 2 + 1) * 256 + colw + ln] = m;
            }
        }
        __syncthreads();
        if (tid < 512) {
            int bl = tid >> 8, c = tid & 255;
            float v = fmaxf(part[(bl * 2 + 0) * 256 + c], part[(bl * 2 + 1) * 256 + c]);
            int bg = by * 2 + bl;
            out[(size_t)bg * E_ + n0 + c] = v + bias[n0 + c] + NF[(size_t)bg * E_ + n0 + c];
        }
    }
}

// ---------------- K6: BN column stats from f16 Hb ----------------
__global__ __launch_bounds__(256) void stats_kernel(
        const _Float16* __restrict__ Hbh, double* __restrict__ stats) {
    int blk = blockIdx.x, tid = threadIdx.x;
    int c0 = tid * 4;
    double s[4] = {0, 0, 0, 0}, q[4] = {0, 0, 0, 0};
    for (int r = 0; r < 96; ++r) {
        const half4v v = *(const half4v*)&Hbh[(size_t)(blk * 96 + r) * H_ + c0];
#pragma unroll
        for (int c = 0; c < 4; ++c) {
            float f = (float)v[c];
            s[c] += f;
            q[c] += (double)f * (double)f;
        }
    }
#pragma unroll
    for (int c = 0; c < 4; ++c) {
        atomicAdd(&stats[c0 + c], s[c]);
        atomicAdd(&stats[H_ + c0 + c], q[c]);
    }
}

// ---------------- K7: finalize BN -> scale/shift ----------------
__global__ void finalize_kernel(const double* __restrict__ stats,
                                const float* __restrict__ gamma,
                                const float* __restrict__ beta,
                                float* __restrict__ scsh) {
    int c = blockIdx.x * 256 + threadIdx.x;
    if (c >= H_) return;
    double mean = stats[c] / (double)M1;
    double var  = stats[H_ + c] / (double)M1 - mean * mean;
    float sc = gamma[c] * (float)(1.0 / sqrt(var + 1e-5));
    float sh = beta[c] - (float)mean * sc;
    scsh[c] = sc;
    scsh[H_ + c] = sh;
}

// ---------------- K8: BN-apply + ReLU -> A2h (f16) ----------------
__global__ __launch_bounds__(256) void bnrelu_kernel(
        const _Float16* __restrict__ Hbh, const float* __restrict__ scsh,
        _Float16* __restrict__ A2h) {
    size_t i = (size_t)blockIdx.x * 256 + threadIdx.x;
    size_t e0 = i * 8;
    int col0 = (int)(e0 & (H_ - 1));
    half8 v = *(const half8*)&Hbh[e0];
    float4 sc0 = *(const float4*)&scsh[col0];
    float4 sc1 = *(const float4*)&scsh[col0 + 4];
    float4 sh0 = *(const float4*)&scsh[H_ + col0];
    float4 sh1 = *(const float4*)&scsh[H_ + col0 + 4];
    half8 o;
    o[0] = (_Float16)fmaxf(0.f, (float)v[0] * sc0.x + sh0.x);
    o[1] = (_Float16)fmaxf(0.f, (float)v[1] * sc0.y + sh0.y);
    o[2] = (_Float16)fmaxf(0.f, (float)v[2] * sc0.z + sh0.z);
    o[3] = (_Float16)fmaxf(0.f, (float)v[3] * sc0.w + sh0.w);
    o[4] = (_Float16)fmaxf(0.f, (float)v[4] * sc1.x + sh1.x);
    o[5] = (_Float16)fmaxf(0.f, (float)v[5] * sc1.y + sh1.y);
    o[6] = (_Float16)fmaxf(0.f, (float)v[6] * sc1.z + sh1.z);
    o[7] = (_Float16)fmaxf(0.f, (float)v[7] * sc1.w + sh1.w);
    *(half8*)&A2h[e0] = o;
}

// ---------------- launch ----------------
extern "C" void kernel_launch(void* const* d_in, const int* in_sizes, int n_in,
                              void* d_out, int out_size, void* d_ws, size_t ws_size,
                              hipStream_t stream) {
    (void)in_sizes; (void)n_in; (void)out_size; (void)ws_size;
    const float* base  = (const float*)d_in[0];
    const float* atten = (const float*)d_in[1];
    // d_in[2] = pid: unused (uniform contiguous groups of 4 by construction)
    const float* W_dyn = (const float*)d_in[3];
    const float* b_dyn = (const float*)d_in[4];
    const float* W_lin = (const float*)d_in[5];
    const float* b_lin = (const float*)d_in[6];
    const float* W1    = (const float*)d_in[7];
    const float* b1    = (const float*)d_in[8];
    const float* gamma = (const float*)d_in[9];
    const float* beta  = (const float*)d_in[10];
    const float* W2    = (const float*)d_in[11];
    const float* b2    = (const float*)d_in[12];
    float* out = (float*)d_out;

    char* wsp = (char*)d_ws;
    int*      idx   = (int*)(wsp);                       // 196608 B
    float*    Y     = (float*)(wsp + 196608);            // 786432 B
    float*    NF    = (float*)(wsp + 983040);            // 4 MB
    double*   stats = (double*)(wsp + 5177344);          // 16 KB
    float*    scsh  = (float*)(wsp + 5193728);           // 8 KB
    _Float16* W1h   = (_Float16*)(wsp + 5201920);        // 1 MB
    _Float16* W2h   = (_Float16*)(wsp + 6250496);        // 4 MB
    _Float16* Xh    = (_Float16*)(wsp + 10444800);       // 49152x512 f16 = 50.3 MB
    _Float16* Hbh   = (_Float16*)(wsp + 60776448);       // 49152x1024 f16 = 100.7 MB
    _Float16* A2h   = (_Float16*)(wsp + 161439744);      // 49152x1024 f16 = 100.7 MB
                                                         // total ~250 MiB

    zero_stats_kernel<<<8, 256, 0, stream>>>(stats);
    topk_kernel<<<B_, 256, 0, stream>>>(atten, idx);
    convw_kernel<<<2560, 256, 0, stream>>>(W1, W2, W1h, W2h);
    gather_kernel<<<M1 / 4, 256, 0, stream>>>(base, idx, W_dyn, b_dyn, Xh, Y);
    newfeat_kernel<<<B_ / 4, 256, 0, stream>>>(Y, W_lin, b_lin, NF);
    gemm_cnt<512, 1, 4><<<1024, 768, 0, stream>>>(Xh, W1h, b1, nullptr, Hbh, nullptr);
    stats_kernel<<<B_, 256, 0, stream>>>(Hbh, stats);
    finalize_kernel<<<4, 256, 0, stream>>>(stats, gamma, beta, scsh);
    bnrelu_kernel<<<(M1 * H_ / 8) / 256, 256, 0, stream>>>(Hbh, scsh, A2h);
    gemm_cnt<1024, 2, 8><<<2048, 768, 0, stream>>>(A2h, W2h, b2, NF, nullptr, out);
}

// Round 7
// 541.976 us; speedup vs baseline: 1.6426x; 1.2423x over previous
//
#include <hip/hip_runtime.h>
#include <math.h>

#define B_   512
#define N_   193
#define D_   512
#define E_   2048
#define KTOK 96
#define H_   1024
#define M1   (B_ * KTOK)      // 49152
#define KGD  (KTOK * 4)       // 384

typedef _Float16 half8 __attribute__((ext_vector_type(8)));
typedef _Float16 half4v __attribute__((ext_vector_type(4)));
typedef float floatx4 __attribute__((ext_vector_type(4)));

// async global->LDS, 16B per lane; LDS dest = wave-uniform base + lane*16
__device__ __forceinline__ void gll16(const _Float16* g, _Float16* l) {
    __builtin_amdgcn_global_load_lds(
        (const __attribute__((address_space(1))) unsigned int*)(const void*)g,
        (__attribute__((address_space(3))) unsigned int*)(void*)l, 16, 0, 0);
}

// ---------------- K0: zero BN stats ----------------
__global__ void zero_stats_kernel(double* stats) {
    int i = blockIdx.x * 256 + threadIdx.x;
    if (i < 2 * H_) stats[i] = 0.0;
}

// ---------------- K1: exact stable top-k (rank count) ----------------
__global__ void topk_kernel(const float* __restrict__ atten, int* __restrict__ idx) {
    __shared__ float s[N_];
    int b = blockIdx.x;
    const float* row = atten + (size_t)b * N_ * N_;   // atten[b, 0, :]
    for (int i = threadIdx.x; i < N_; i += blockDim.x)
        s[i] = (i == 0) ? -1.0f : row[i];
    __syncthreads();
    for (int i = threadIdx.x; i < N_; i += blockDim.x) {
        float v = s[i];
        int rank = 0;
        for (int j = 0; j < N_; ++j) {
            float u = s[j];
            rank += (u > v) || (u == v && j < i);
        }
        if (rank < KTOK) idx[b * KTOK + rank] = i;
    }
}

// ---------------- K2: gather + l2norm -> Xh (f16) + dyn-proj stage 1 (Y) ----------------
__global__ __launch_bounds__(256) void gather_kernel(
        const float* __restrict__ base, const int* __restrict__ idx,
        const float* __restrict__ W_dyn, const float* __restrict__ b_dyn,
        _Float16* __restrict__ Xh, float* __restrict__ Y) {
    int ln = threadIdx.x & 63, wv = threadIdx.x >> 6;
    int rowid = blockIdx.x * 4 + wv;        // 0..49151 = b*96 + t
    int b = rowid / KTOK, t = rowid - b * KTOK;
    int tok = idx[rowid];
    const float4* src = (const float4*)(base + ((size_t)b * N_ + tok) * D_);
    float4 v0 = src[ln * 2], v1 = src[ln * 2 + 1];

    float vals[5];
    vals[0] = v0.x * v0.x + v0.y * v0.y + v0.z * v0.z + v0.w * v0.w
            + v1.x * v1.x + v1.y * v1.y + v1.z * v1.z + v1.w * v1.w;
#pragma unroll
    for (int r = 0; r < 4; ++r) {
        const float4* wr = (const float4*)(W_dyn + r * D_);
        float4 w0 = wr[ln * 2], w1 = wr[ln * 2 + 1];
        vals[1 + r] = v0.x * w0.x + v0.y * w0.y + v0.z * w0.z + v0.w * w0.w
                    + v1.x * w1.x + v1.y * w1.y + v1.z * w1.z + v1.w * w1.w;
    }
#pragma unroll
    for (int c = 0; c < 5; ++c)
#pragma unroll
        for (int o = 32; o > 0; o >>= 1) vals[c] += __shfl_xor(vals[c], o, 64);

    float inv = 1.0f / (sqrtf(vals[0]) + 1e-8f);
    half8 o8;
    o8[0] = (_Float16)(v0.x * inv); o8[1] = (_Float16)(v0.y * inv);
    o8[2] = (_Float16)(v0.z * inv); o8[3] = (_Float16)(v0.w * inv);
    o8[4] = (_Float16)(v1.x * inv); o8[5] = (_Float16)(v1.y * inv);
    o8[6] = (_Float16)(v1.z * inv); o8[7] = (_Float16)(v1.w * inv);
    *(half8*)&Xh[(size_t)rowid * D_ + ln * 8] = o8;
    if (ln == 0) {
        int g = b >> 2;
        int n = (b & 3) * KTOK + t;
#pragma unroll
        for (int r = 0; r < 4; ++r)
            Y[(size_t)(g * 4 + r) * KGD + n] = vals[1 + r] + b_dyn[r];
    }
}

// ---------------- K3: new_feats = l2norm(Y @ W_lin^T + b_lin) (fp32, small) ----------------
__global__ __launch_bounds__(256) void newfeat_kernel(
        const float* __restrict__ Y, const float* __restrict__ W_lin,
        const float* __restrict__ b_lin, float* __restrict__ NF) {
    __shared__ float sy[4][KGD];
    __shared__ float red[4][4];
    __shared__ float tot[4];
    int b0 = blockIdx.x * 4;
    int tid = threadIdx.x;
    for (int l = tid; l < 4 * KGD; l += 256)
        sy[l / KGD][l % KGD] = Y[(size_t)b0 * KGD + l];
    __syncthreads();

    float out[4][8];
    float ssq[4] = {0.f, 0.f, 0.f, 0.f};
#pragma unroll
    for (int q = 0; q < 8; ++q) {
        int o = tid + 256 * q;
        float a0 = 0.f, a1 = 0.f, a2 = 0.f, a3 = 0.f;
        const float4* wr = (const float4*)(W_lin + (size_t)o * KGD);
        for (int i4 = 0; i4 < KGD / 4; ++i4) {
            float4 w  = wr[i4];
            float4 s0 = *(const float4*)&sy[0][i4 * 4];
            float4 s1 = *(const float4*)&sy[1][i4 * 4];
            float4 s2 = *(const float4*)&sy[2][i4 * 4];
            float4 s3 = *(const float4*)&sy[3][i4 * 4];
            a0 += w.x * s0.x + w.y * s0.y + w.z * s0.z + w.w * s0.w;
            a1 += w.x * s1.x + w.y * s1.y + w.z * s1.z + w.w * s1.w;
            a2 += w.x * s2.x + w.y * s2.y + w.z * s2.z + w.w * s2.w;
            a3 += w.x * s3.x + w.y * s3.y + w.z * s3.z + w.w * s3.w;
        }
        float bl = b_lin[o];
        out[0][q] = a0 + bl; out[1][q] = a1 + bl;
        out[2][q] = a2 + bl; out[3][q] = a3 + bl;
#pragma unroll
        for (int r = 0; r < 4; ++r) ssq[r] += out[r][q] * out[r][q];
    }

    int lane = tid & 63, wid = tid >> 6;
#pragma unroll
    for (int c = 0; c < 4; ++c) {
        float v = ssq[c];
        for (int o = 32; o > 0; o >>= 1) v += __shfl_down(v, o, 64);
        if (lane == 0) red[c][wid] = v;
    }
    __syncthreads();
    if (tid < 4) tot[tid] = red[tid][0] + red[tid][1] + red[tid][2] + red[tid][3];
    __syncthreads();
#pragma unroll
    for (int r = 0; r < 4; ++r) {
        float norm = sqrtf(tot[r]) + 1e-8f;
#pragma unroll
        for (int q = 0; q < 8; ++q) {
            int o = tid + 256 * q;
            NF[(size_t)(b0 + r) * E_ + o] = out[r][q] / norm;
        }
    }
}

// ---------------- K4: convert W1, W2 to f16 ----------------
__global__ __launch_bounds__(256) void convw_kernel(
        const float* __restrict__ W1, const float* __restrict__ W2,
        _Float16* __restrict__ W1h, _Float16* __restrict__ W2h) {
    int i = blockIdx.x * 256 + threadIdx.x;
    if (i < 131072) {                       // W1: 1024*512/4
        float4 v = *(const float4*)&W1[(size_t)i * 4];
        half4v o = {(_Float16)v.x, (_Float16)v.y, (_Float16)v.z, (_Float16)v.w};
        *(half4v*)&W1h[(size_t)i * 4] = o;
    } else {                                // W2: 2048*1024/4
        int j = i - 131072;
        float4 v = *(const float4*)&W2[(size_t)j * 4];
        half4v o = {(_Float16)v.x, (_Float16)v.y, (_Float16)v.z, (_Float16)v.w};
        *(half4v*)&W2h[(size_t)j * 4] = o;
    }
}

// ---------------- gemm1s: r5-structure GEMM + fused BN-stats epilogue ----------------
// C = A@B^T + bias -> f16; per-block column sum/sumsq over 192 rows -> f64 atomics.
__global__ __launch_bounds__(512, 2) void gemm1s(
        const _Float16* __restrict__ A, const _Float16* __restrict__ Bm,
        const float* __restrict__ bias, _Float16* __restrict__ Cf16,
        double* __restrict__ stats) {
    constexpr int KA = 512, NS = 16, NBX = 4;
    __shared__ _Float16 Sl[4][14336];       // slot: A [4kg][192][8] | B [4kg][256][8]
    int tid = threadIdx.x;
    int ln = tid & 63, w = tid >> 6;
    int wr = w >> 2, wc = w & 3;
    int rid = blockIdx.x;
    int q = rid >> 3;
    int bx = q & (NBX - 1);
    int by = ((q / NBX) << 3) | (rid & 7);
    int n0 = bx * 256, m0 = by * 192;

    bool isA = (w < 4);
    const _Float16* sg[4];
    int ld[4];
    if (isA) {
#pragma unroll
        for (int i = 0; i < 3; ++i) {
            int j = w * 3 + i;
            int u = j * 64 + ln;
            int kg = u / 192, row = u - kg * 192;
            sg[i] = A + (size_t)(m0 + row) * KA + kg * 8;
            ld[i] = j * 512;
        }
        sg[3] = sg[0]; ld[3] = ld[0];
    } else {
#pragma unroll
        for (int i = 0; i < 4; ++i) {
            int j = (w - 4) * 4 + i;
            int u = j * 64 + ln;
            int kg = u >> 8, col = u & 255;
            sg[i] = Bm + (size_t)(n0 + col) * KA + kg * 8;
            ld[i] = 6144 + j * 512;
        }
    }

#define CSTAGE(s) { int ko = (s) * 32; _Float16* dst = &Sl[(s) & 3][0];        \
    if (isA) { gll16(sg[0] + ko, dst + ld[0]); gll16(sg[1] + ko, dst + ld[1]); \
               gll16(sg[2] + ko, dst + ld[2]); }                               \
    else     { gll16(sg[0] + ko, dst + ld[0]); gll16(sg[1] + ko, dst + ld[1]); \
               gll16(sg[2] + ko, dst + ld[2]); gll16(sg[3] + ko, dst + ld[3]); } }
#define WAITV(na, nb) { if (isA) asm volatile("s_waitcnt vmcnt(" #na ")" ::: "memory"); \
                        else     asm volatile("s_waitcnt vmcnt(" #nb ")" ::: "memory"); }

    int aofs[6], bofs[4];
#pragma unroll
    for (int f = 0; f < 6; ++f)
        aofs[f] = ((ln >> 4) * 192 + wr * 96 + f * 16 + (ln & 15)) * 8;
#pragma unroll
    for (int n = 0; n < 4; ++n)
        bofs[n] = 6144 + ((ln >> 4) * 256 + wc * 64 + n * 16 + (ln & 15)) * 8;

    floatx4 zero = {0.f, 0.f, 0.f, 0.f};
    floatx4 acc[6][4];
#pragma unroll
    for (int i = 0; i < 6; ++i)
#pragma unroll
        for (int j = 0; j < 4; ++j) acc[i][j] = zero;

    CSTAGE(0); CSTAGE(1); CSTAGE(2);
    WAITV(6, 8);
    __builtin_amdgcn_s_barrier();

    for (int s = 0; s < NS; ++s) {
        const _Float16* SL = &Sl[s & 3][0];
        half8 bv[4], av[3];
#pragma unroll
        for (int n = 0; n < 4; ++n) bv[n] = *(const half8*)&SL[bofs[n]];
#pragma unroll
        for (int f = 0; f < 3; ++f) av[f] = *(const half8*)&SL[aofs[f]];
        if (s + 3 < NS) CSTAGE(s + 3);
        __builtin_amdgcn_sched_barrier(0);
        __builtin_amdgcn_s_barrier();
        asm volatile("s_waitcnt lgkmcnt(0)" ::: "memory");
        __builtin_amdgcn_sched_barrier(0);
        __builtin_amdgcn_s_setprio(1);
#pragma unroll
        for (int f = 0; f < 3; ++f)
#pragma unroll
            for (int n = 0; n < 4; ++n)
                acc[f][n] = __builtin_amdgcn_mfma_f32_16x16x32_f16(av[f], bv[n], acc[f][n], 0, 0, 0);
        __builtin_amdgcn_s_setprio(0);
        __builtin_amdgcn_sched_barrier(0);
        __builtin_amdgcn_s_barrier();
        half8 av2[3];
#pragma unroll
        for (int f = 0; f < 3; ++f) av2[f] = *(const half8*)&SL[aofs[3 + f]];
        __builtin_amdgcn_sched_barrier(0);
        if (s + 1 < NS) {
            if (s + 3 < NS)      { WAITV(6, 8); }
            else if (s + 2 < NS) { WAITV(3, 4); }
            else                 { WAITV(0, 0); }
        }
        __builtin_amdgcn_s_barrier();
        asm volatile("s_waitcnt lgkmcnt(0)" ::: "memory");
        __builtin_amdgcn_sched_barrier(0);
        __builtin_amdgcn_s_setprio(1);
#pragma unroll
        for (int f = 0; f < 3; ++f)
#pragma unroll
            for (int n = 0; n < 4; ++n)
                acc[3 + f][n] = __builtin_amdgcn_mfma_f32_16x16x32_f16(av2[f], bv[n], acc[3 + f][n], 0, 0, 0);
        __builtin_amdgcn_s_setprio(0);
        __builtin_amdgcn_sched_barrier(0);
        __builtin_amdgcn_s_barrier();
    }
#undef CSTAGE
#undef WAITV

    // epilogue: C-write + per-column stats (sum, sumsq over this block's 192 rows)
    float cs[4] = {0.f, 0.f, 0.f, 0.f}, cq[4] = {0.f, 0.f, 0.f, 0.f};
#pragma unroll
    for (int f = 0; f < 6; ++f) {
        int row = m0 + wr * 96 + f * 16 + (ln >> 4) * 4;
#pragma unroll
        for (int n = 0; n < 4; ++n) {
            int col = n0 + wc * 64 + n * 16 + (ln & 15);
            float bb = bias[col];
#pragma unroll
            for (int r = 0; r < 4; ++r) {
                float v = acc[f][n][r] + bb;
                Cf16[(size_t)(row + r) * H_ + col] = (_Float16)v;
                cs[n] += v; cq[n] += v * v;
            }
        }
    }
#pragma unroll
    for (int n = 0; n < 4; ++n) {
        cs[n] += __shfl_xor(cs[n], 16); cs[n] += __shfl_xor(cs[n], 32);
        cq[n] += __shfl_xor(cq[n], 16); cq[n] += __shfl_xor(cq[n], 32);
    }
    float* sp = (float*)&Sl[0][0];          // reuse LDS: [2 wr][256 col][2]
    if (ln < 16) {
#pragma unroll
        for (int n = 0; n < 4; ++n) {
            int c = wc * 64 + n * 16 + ln;
            sp[(wr * 256 + c) * 2 + 0] = cs[n];
            sp[(wr * 256 + c) * 2 + 1] = cq[n];
        }
    }
    __syncthreads();
    if (tid < 256) {
        float s0 = sp[tid * 2]     + sp[(256 + tid) * 2];
        float q0 = sp[tid * 2 + 1] + sp[(256 + tid) * 2 + 1];
        atomicAdd(&stats[n0 + tid], (double)s0);
        atomicAdd(&stats[H_ + n0 + tid], (double)q0);
    }
}

// ---------------- K7: finalize BN -> f16 scale/shift ----------------
__global__ void finalize_kernel(const double* __restrict__ stats,
                                const float* __restrict__ gamma,
                                const float* __restrict__ beta,
                                _Float16* __restrict__ scsh16) {
    int c = blockIdx.x * 256 + threadIdx.x;
    if (c >= H_) return;
    double mean = stats[c] / (double)M1;
    double var  = stats[H_ + c] / (double)M1 - mean * mean;
    float sc = gamma[c] * (float)(1.0 / sqrt(var + 1e-5));
    float sh = beta[c] - (float)mean * sc;
    scsh16[c] = (_Float16)sc;
    scsh16[H_ + c] = (_Float16)sh;
}

// ---------------- gemm2f: GEMM + fused BN-apply/ReLU on A + fused maxpool ----------------
// A-waves reg-stage Hbh: issue loads for slot s+3 at slot s; transform (f32
// scale/shift/relu, scsh f16 in LDS) + ds_write at slot s+1 targeting the free
// ring slot (s+3 written 2 slots before consumption). B-waves: gll16 + counted
// vmcnt (never 0 mid-loop), waits placed after MFMA. 2 named regsets (rule #20).
__device__ __forceinline__ half8 bnrelu8(half8 h, const _Float16* scp, const _Float16* shp) {
    half8 s = *(const half8*)scp, t = *(const half8*)shp, o;
#pragma unroll
    for (int e = 0; e < 8; ++e) {
        float v = (float)h[e] * (float)s[e] + (float)t[e];
        o[e] = (_Float16)fmaxf(v, 0.f);
    }
    return o;
}

__global__ __launch_bounds__(512, 2) void gemm2f(
        const _Float16* __restrict__ Hb, const _Float16* __restrict__ Bm,
        const _Float16* __restrict__ scsh16, const float* __restrict__ bias,
        const float* __restrict__ NF, float* __restrict__ out) {
    constexpr int KA = 1024, NS = 32, NBX = 8;
    __shared__ _Float16 Sl[4][14336];       // slot: A [4kg][192][8] | B [4kg][256][8]
    __shared__ _Float16 scL[H_], shL[H_];
    int tid = threadIdx.x;
    int ln = tid & 63, w = tid >> 6;
    int wr = w >> 2, wc = w & 3;
    int rid = blockIdx.x;
    int qq = rid >> 3;
    int bx = qq & (NBX - 1);
    int by = ((qq / NBX) << 3) | (rid & 7);
    int n0 = bx * 256, m0 = by * 192;
    bool isA = (w < 4);

    for (int i = tid; i < H_; i += 512) { scL[i] = scsh16[i]; shL[i] = scsh16[H_ + i]; }

    const _Float16 *sgA0 = Hb, *sgA1 = Hb, *sgA2 = Hb;
    int ldA0 = 0, ldA1 = 0, ldA2 = 0, kgA0 = 0, kgA1 = 0, kgA2 = 0;
    const _Float16* sgB[4] = {Bm, Bm, Bm, Bm};
    int ldB[4] = {6144, 6144, 6144, 6144};
    if (isA) {
        { int j = w * 3 + 0; int u = j * 64 + ln; kgA0 = u / 192; int row = u - kgA0 * 192;
          sgA0 = Hb + (size_t)(m0 + row) * KA + kgA0 * 8; ldA0 = j * 512; }
        { int j = w * 3 + 1; int u = j * 64 + ln; kgA1 = u / 192; int row = u - kgA1 * 192;
          sgA1 = Hb + (size_t)(m0 + row) * KA + kgA1 * 8; ldA1 = j * 512; }
        { int j = w * 3 + 2; int u = j * 64 + ln; kgA2 = u / 192; int row = u - kgA2 * 192;
          sgA2 = Hb + (size_t)(m0 + row) * KA + kgA2 * 8; ldA2 = j * 512; }
    } else {
#pragma unroll
        for (int i = 0; i < 4; ++i) {
            int j = (w - 4) * 4 + i;
            int u = j * 64 + ln;
            int kg = u >> 8, col = u & 255;
            sgB[i] = Bm + (size_t)(n0 + col) * KA + kg * 8;
            ldB[i] = 6144 + j * 512;
        }
    }

#define A_ISSUE(t, Ra, Rb, Rc) { Ra = *(const half8*)(sgA0 + (size_t)(t) * 32); \
    Rb = *(const half8*)(sgA1 + (size_t)(t) * 32);                              \
    Rc = *(const half8*)(sgA2 + (size_t)(t) * 32); }
#define A_XFRM(t, Ra, Rb, Rc) { _Float16* dst = &Sl[(t) & 3][0]; int c0 = (t) * 32; \
    *(half8*)(dst + ldA0 + ln * 8) = bnrelu8(Ra, &scL[c0 + kgA0 * 8], &shL[c0 + kgA0 * 8]); \
    *(half8*)(dst + ldA1 + ln * 8) = bnrelu8(Rb, &scL[c0 + kgA1 * 8], &shL[c0 + kgA1 * 8]); \
    *(half8*)(dst + ldA2 + ln * 8) = bnrelu8(Rc, &scL[c0 + kgA2 * 8], &shL[c0 + kgA2 * 8]); }
#define B_STAGE(t) { int ko = (t) * 32; _Float16* dst = &Sl[(t) & 3][0]; \
    gll16(sgB[0] + ko, dst + ldB[0]); gll16(sgB[1] + ko, dst + ldB[1]); \
    gll16(sgB[2] + ko, dst + ldB[2]); gll16(sgB[3] + ko, dst + ldB[3]); }

    int aofs[6], bofs[4];
#pragma unroll
    for (int f = 0; f < 6; ++f)
        aofs[f] = ((ln >> 4) * 192 + wr * 96 + f * 16 + (ln & 15)) * 8;
#pragma unroll
    for (int n = 0; n < 4; ++n)
        bofs[n] = 6144 + ((ln >> 4) * 256 + wc * 64 + n * 16 + (ln & 15)) * 8;

    floatx4 zero = {0.f, 0.f, 0.f, 0.f};
    floatx4 acc[6][4];
#pragma unroll
    for (int i = 0; i < 6; ++i)
#pragma unroll
        for (int j = 0; j < 4; ++j) acc[i][j] = zero;

    half8 e0a, e0b, e0c, e1a, e1b, e1c;     // even/odd regsets

    // prologue: scsh visible; A pre-writes slots 0,1 (loads 2 in flight); B stages 0-2
    if (isA) { A_ISSUE(0, e0a, e0b, e0c); A_ISSUE(1, e1a, e1b, e1c); }
    else     { B_STAGE(0); B_STAGE(1); B_STAGE(2); }
    asm volatile("s_waitcnt lgkmcnt(0)" ::: "memory");
    __builtin_amdgcn_s_barrier();
    if (isA) {
        A_XFRM(0, e0a, e0b, e0c);           // compiler waits vmcnt(3)
        A_ISSUE(2, e0a, e0b, e0c);
        A_XFRM(1, e1a, e1b, e1c);
    } else {
        asm volatile("s_waitcnt vmcnt(8)" ::: "memory");
    }
    asm volatile("s_waitcnt lgkmcnt(0)" ::: "memory");
    __builtin_amdgcn_s_barrier();

#define SLOT(s, Ia, Ib, Ic, Xa, Xb, Xc) {                                       \
    const _Float16* SL = &Sl[(s) & 3][0];                                       \
    half8 bv[4], av[3], av2[3];                                                 \
    _Pragma("unroll") for (int n = 0; n < 4; ++n) bv[n] = *(const half8*)&SL[bofs[n]]; \
    _Pragma("unroll") for (int f = 0; f < 3; ++f) av[f] = *(const half8*)&SL[aofs[f]]; \
    if ((s) + 3 < NS) { if (isA) { A_ISSUE((s) + 3, Ia, Ib, Ic); } else { B_STAGE((s) + 3); } } \
    __builtin_amdgcn_sched_barrier(0);                                          \
    __builtin_amdgcn_s_barrier();                                               \
    asm volatile("s_waitcnt lgkmcnt(0)" ::: "memory");                          \
    __builtin_amdgcn_sched_barrier(0);                                          \
    __builtin_amdgcn_s_setprio(1);                                              \
    _Pragma("unroll") for (int f = 0; f < 3; ++f)                               \
        _Pragma("unroll") for (int n = 0; n < 4; ++n)                           \
            acc[f][n] = __builtin_amdgcn_mfma_f32_16x16x32_f16(av[f], bv[n], acc[f][n], 0, 0, 0); \
    __builtin_amdgcn_s_setprio(0);                                              \
    __builtin_amdgcn_sched_barrier(0);                                          \
    __builtin_amdgcn_s_barrier();                                               \
    _Pragma("unroll") for (int f = 0; f < 3; ++f) av2[f] = *(const half8*)&SL[aofs[3 + f]]; \
    __builtin_amdgcn_sched_barrier(0);                                          \
    __builtin_amdgcn_s_barrier();                                               \
    asm volatile("s_waitcnt lgkmcnt(0)" ::: "memory");                          \
    __builtin_amdgcn_sched_barrier(0);                                          \
    __builtin_amdgcn_s_setprio(1);                                              \
    _Pragma("unroll") for (int f = 0; f < 3; ++f)                               \
        _Pragma("unroll") for (int n = 0; n < 4; ++n)                           \
            acc[3 + f][n] = __builtin_amdgcn_mfma_f32_16x16x32_f16(av2[f], bv[n], acc[3 + f][n], 0, 0, 0); \
    __builtin_amdgcn_s_setprio(0);                                              \
    __builtin_amdgcn_sched_barrier(0);                                          \
    if (isA) {                                                                  \
        if ((s) + 2 < NS) { A_XFRM((s) + 2, Xa, Xb, Xc); }                      \
    } else {                                                                    \
        if ((s) + 3 < NS)      { asm volatile("s_waitcnt vmcnt(8)" ::: "memory"); } \
        else if ((s) + 2 < NS) { asm volatile("s_waitcnt vmcnt(4)" ::: "memory"); } \
        else if ((s) + 1 < NS) { asm volatile("s_waitcnt vmcnt(0)" ::: "memory"); } \
    }                                                                           \
    __builtin_amdgcn_s_barrier();                                               \
}

    for (int s = 0; s < NS; s += 2) {
        SLOT(s,     e1a, e1b, e1c, e0a, e0b, e0c);   // issue s+3 (odd)->e1, xfrm s+2 (even)<-e0
        SLOT(s + 1, e0a, e0b, e0c, e1a, e1b, e1c);   // issue s+4 (even)->e0, xfrm s+3 (odd)<-e1
    }
#undef SLOT
#undef A_ISSUE
#undef A_XFRM
#undef B_STAGE

    // fused maxpool over 96 rows (wave-half wr owns one batch) + bias + NF
    int batch = by * 2 + wr;
#pragma unroll
    for (int n = 0; n < 4; ++n) {
        float m = -3.4e38f;
#pragma unroll
        for (int f = 0; f < 6; ++f)
#pragma unroll
            for (int r = 0; r < 4; ++r) m = fmaxf(m, acc[f][n][r]);
        m = fmaxf(m, __shfl_xor(m, 16));
        m = fmaxf(m, __shfl_xor(m, 32));
        if (ln < 16) {
            int col = n0 + wc * 64 + n * 16 + ln;
            out[(size_t)batch * E_ + col] = m + bias[col] + NF[(size_t)batch * E_ + col];
        }
    }
}

// ---------------- launch ----------------
extern "C" void kernel_launch(void* const* d_in, const int* in_sizes, int n_in,
                              void* d_out, int out_size, void* d_ws, size_t ws_size,
                              hipStream_t stream) {
    (void)in_sizes; (void)n_in; (void)out_size; (void)ws_size;
    const float* base  = (const float*)d_in[0];
    const float* atten = (const float*)d_in[1];
    // d_in[2] = pid: unused (uniform contiguous groups of 4 by construction)
    const float* W_dyn = (const float*)d_in[3];
    const float* b_dyn = (const float*)d_in[4];
    const float* W_lin = (const float*)d_in[5];
    const float* b_lin = (const float*)d_in[6];
    const float* W1    = (const float*)d_in[7];
    const float* b1    = (const float*)d_in[8];
    const float* gamma = (const float*)d_in[9];
    const float* beta  = (const float*)d_in[10];
    const float* W2    = (const float*)d_in[11];
    const float* b2    = (const float*)d_in[12];
    float* out = (float*)d_out;

    char* wsp = (char*)d_ws;
    int*      idx    = (int*)(wsp);                      // 196608 B
    float*    Y      = (float*)(wsp + 196608);           // 786432 B
    float*    NF     = (float*)(wsp + 983040);           // 4 MB
    double*   stats  = (double*)(wsp + 5177344);         // 16 KB
    _Float16* scsh16 = (_Float16*)(wsp + 5193728);       // 4 KB
    _Float16* W1h    = (_Float16*)(wsp + 5201920);       // 1 MB
    _Float16* W2h    = (_Float16*)(wsp + 6250496);       // 4 MB
    _Float16* Xh     = (_Float16*)(wsp + 10444800);      // 49152x512 f16 = 50.3 MB
    _Float16* Hbh    = (_Float16*)(wsp + 60776448);      // 49152x1024 f16 = 100.7 MB
                                                         // total ~154 MiB

    zero_stats_kernel<<<8, 256, 0, stream>>>(stats);
    topk_kernel<<<B_, 256, 0, stream>>>(atten, idx);
    convw_kernel<<<2560, 256, 0, stream>>>(W1, W2, W1h, W2h);
    gather_kernel<<<M1 / 4, 256, 0, stream>>>(base, idx, W_dyn, b_dyn, Xh, Y);
    newfeat_kernel<<<B_ / 4, 256, 0, stream>>>(Y, W_lin, b_lin, NF);
    gemm1s<<<1024, 512, 0, stream>>>(Xh, W1h, b1, Hbh, stats);
    finalize_kernel<<<4, 256, 0, stream>>>(stats, gamma, beta, scsh16);
    gemm2f<<<2048, 512, 0, stream>>>(Hbh, W2h, scsh16, b2, NF, out);
}